// Round 1
// baseline (780.883 us; speedup 1.0000x reference)
//
#include <hip/hip_runtime.h>
#include <math.h>

#define DIM 128
#define DIN 20

// ---------------------------------------------------------------- CSR build
__global__ void hist_kernel(const int* __restrict__ ei, int* __restrict__ counts, int E) {
    int e = blockIdx.x * 256 + threadIdx.x;
    if (e < E) atomicAdd(&counts[ei[E + e]], 1);   // row 1 = dst
}

__global__ void scan1_kernel(const int* __restrict__ counts, int* __restrict__ incl,
                             int* __restrict__ blockSums, int N) {
    __shared__ int s[1024];
    int t = threadIdx.x;
    int i = blockIdx.x * 1024 + t;
    s[t] = (i < N) ? counts[i] : 0;
    __syncthreads();
    for (int off = 1; off < 1024; off <<= 1) {
        int x = (t >= off) ? s[t - off] : 0;
        __syncthreads();
        s[t] += x;
        __syncthreads();
    }
    if (i < N) incl[i] = s[t];
    if (t == 1023) blockSums[blockIdx.x] = s[1023];
}

__global__ void scan2_kernel(const int* __restrict__ blockSums, int* __restrict__ blockOff, int G) {
    if (threadIdx.x == 0 && blockIdx.x == 0) {
        int acc = 0;
        for (int b = 0; b < G; ++b) { blockOff[b] = acc; acc += blockSums[b]; }
    }
}

__global__ void scan3_kernel(const int* __restrict__ counts, int* __restrict__ rp,
                             int* __restrict__ cursor, const int* __restrict__ blockOff,
                             int N, int E) {
    int i = blockIdx.x * 1024 + threadIdx.x;
    if (i < N) {
        int excl = rp[i] - counts[i] + blockOff[blockIdx.x];
        rp[i] = excl;
        cursor[i] = excl;
    }
    if (i == 0) rp[N] = E;
}

__global__ void fill_kernel(const int* __restrict__ ei, int* __restrict__ cursor,
                            int* __restrict__ srcS, int E) {
    int e = blockIdx.x * 256 + threadIdx.x;
    if (e >= E) return;
    int d = ei[E + e];
    int pos = atomicAdd(&cursor[d], 1);
    srcS[pos] = ei[e];                               // row 0 = src
}

// ---------------------------------------------------------------- pre GEMM  h = x @ pre_w   [N,20]x[20,128]
__global__ __launch_bounds__(128) void pre_gemm_kernel(const float* __restrict__ x,
                                                       const float* __restrict__ w,
                                                       float* __restrict__ h, int N) {
    __shared__ float ws_[DIN * DIM];
    __shared__ float xr[DIN];
    int tid = threadIdx.x;
    for (int i = tid; i < DIN * DIM; i += 128) ws_[i] = w[i];
    for (int row = blockIdx.x; row < N; row += gridDim.x) {
        __syncthreads();
        if (tid < DIN) xr[tid] = x[(size_t)row * DIN + tid];
        __syncthreads();
        float acc = 0.f;
        #pragma unroll
        for (int k = 0; k < DIN; ++k) acc = fmaf(xr[k], ws_[k * DIM + tid], acc);
        h[(size_t)row * DIM + tid] = acc;
    }
}

// ---------------------------------------------------------------- fused 4-output GEMM  [N,128] x [128,128] x4
// blockIdx.x = cb (0..7): cb>>1 selects weight/output, (cb&1)*64 = column half.
#define BM 64
#define BN 64
#define BKK 32
__global__ __launch_bounds__(256) void gemm4_kernel(
        const float* __restrict__ A,
        const float* __restrict__ Wk, const float* __restrict__ Wq,
        const float* __restrict__ Wv, const float* __restrict__ Wsp,
        float* __restrict__ K, float* __restrict__ Q,
        float* __restrict__ V, float* __restrict__ S, int N) {
    __shared__ float As[BKK][BM + 4];   // +4 keeps float4 alignment, breaks bank clash
    __shared__ float Bs[BKK][BN];
    int cb = blockIdx.x;
    int row0 = blockIdx.y * BM;
    const float* W = (cb < 2) ? Wk : (cb < 4) ? Wq : (cb < 6) ? Wv : Wsp;
    float* O       = (cb < 2) ? K  : (cb < 4) ? Q  : (cb < 6) ? V  : S;
    int ncol0 = (cb & 1) * 64;
    int tid = threadIdx.x;
    int tx = tid & 15, ty = tid >> 4;
    float acc[4][4] = {};
    for (int k0 = 0; k0 < DIM; k0 += BKK) {
        #pragma unroll
        for (int v = 0; v < 2; ++v) {                 // A tile 64x32, transposed into LDS
            int lin = tid + v * 256;
            int r = lin >> 3;
            int kc = (lin & 7) << 2;
            float4 a4 = make_float4(0.f, 0.f, 0.f, 0.f);
            if (row0 + r < N) a4 = *(const float4*)(A + (size_t)(row0 + r) * DIM + k0 + kc);
            As[kc + 0][r] = a4.x; As[kc + 1][r] = a4.y;
            As[kc + 2][r] = a4.z; As[kc + 3][r] = a4.w;
        }
        #pragma unroll
        for (int v = 0; v < 2; ++v) {                 // B tile 32x64
            int lin = tid + v * 256;
            int r = lin >> 4;
            int c4 = (lin & 15) << 2;
            *(float4*)&Bs[r][c4] = *(const float4*)(W + (size_t)(k0 + r) * DIM + ncol0 + c4);
        }
        __syncthreads();
        #pragma unroll
        for (int k = 0; k < BKK; ++k) {
            float4 av = *(const float4*)&As[k][ty * 4];
            float4 bv = *(const float4*)&Bs[k][tx * 4];
            float ar[4] = {av.x, av.y, av.z, av.w};
            float br[4] = {bv.x, bv.y, bv.z, bv.w};
            #pragma unroll
            for (int i = 0; i < 4; ++i)
                #pragma unroll
                for (int j = 0; j < 4; ++j)
                    acc[i][j] = fmaf(ar[i], br[j], acc[i][j]);
        }
        __syncthreads();
    }
    #pragma unroll
    for (int i = 0; i < 4; ++i) {
        int r = row0 + ty * 4 + i;
        if (r < N) {
            float4 o = make_float4(acc[i][0], acc[i][1], acc[i][2], acc[i][3]);
            *(float4*)(O + (size_t)r * DIM + ncol0 + tx * 4) = o;
        }
    }
}

// ---------------------------------------------------------------- pull aggregation (CSR by dst)
__global__ __launch_bounds__(128) void aggregate_kernel(
        const float* __restrict__ K, const float* __restrict__ Q, const float* __restrict__ V,
        const int* __restrict__ rp, const int* __restrict__ srcS,
        float* __restrict__ out, int N) {
    int i = blockIdx.x;
    int c = threadIdx.x;
    float kv = K[(size_t)i * DIM + c];
    float acc = 0.f;
    int beg = rp[i], end = rp[i + 1];
    for (int e = beg; e < end; ++e) {
        int j = srcS[e];
        size_t jb = (size_t)j * DIM;
        float s = kv + Q[jb + c];
        float sig = __builtin_amdgcn_rcpf(1.f + __expf(-s));
        acc = fmaf(sig, V[jb + c], acc);
    }
    out[(size_t)i * DIM + c] += acc;    // out pre-filled with h @ Ws
}

// ---------------------------------------------------------------- BN column stats
__global__ __launch_bounds__(128) void colstats_kernel(const float* __restrict__ h,
                                                       float* __restrict__ colsum,
                                                       float* __restrict__ colsq, int N) {
    int c = threadIdx.x;
    float s = 0.f, sq = 0.f;
    for (int r = blockIdx.x; r < N; r += gridDim.x) {
        float v = h[(size_t)r * DIM + c];
        s += v;
        sq = fmaf(v, v, sq);
    }
    atomicAdd(&colsum[c], s);
    atomicAdd(&colsq[c], sq);
}

__global__ void scaleshift_kernel(const float* __restrict__ colsum, const float* __restrict__ colsq,
                                  const float* __restrict__ gamma, const float* __restrict__ beta,
                                  float* __restrict__ scale, float* __restrict__ shift, float invN) {
    int c = threadIdx.x;
    float mu  = colsum[c] * invN;
    float var = colsq[c] * invN - mu * mu;
    float sc  = gamma[c] * rsqrtf(var + 1e-5f);
    scale[c] = sc;
    shift[c] = beta[c] - mu * sc;
}

// ---------------------------------------------------------------- BN apply + ReLU + row L2 norm (in place)
__global__ __launch_bounds__(256) void finalize_kernel(float* __restrict__ h,
                                                       const float* __restrict__ scale,
                                                       const float* __restrict__ shift, int N) {
    int row = blockIdx.x * 4 + (threadIdx.x >> 6);
    int lane = threadIdx.x & 63;
    if (row >= N) return;
    size_t base = (size_t)row * DIM;
    float y0 = fmaf(h[base + lane],      scale[lane],      shift[lane]);
    float y1 = fmaf(h[base + lane + 64], scale[lane + 64], shift[lane + 64]);
    y0 = fmaxf(y0, 0.f);
    y1 = fmaxf(y1, 0.f);
    float ss = y0 * y0 + y1 * y1;
    #pragma unroll
    for (int off = 32; off; off >>= 1) ss += __shfl_xor(ss, off);
    float inv = 1.0f / fmaxf(sqrtf(ss), 1e-12f);
    h[base + lane]      = y0 * inv;
    h[base + lane + 64] = y1 * inv;
}

// ---------------------------------------------------------------- launch
extern "C" void kernel_launch(void* const* d_in, const int* in_sizes, int n_in,
                              void* d_out, int out_size, void* d_ws, size_t ws_size,
                              hipStream_t stream) {
    const float* x     = (const float*)d_in[0];
    const int*   ei    = (const int*)d_in[1];
    const float* pre_w = (const float*)d_in[2];
    const float* pre_g = (const float*)d_in[3];
    const float* pre_b = (const float*)d_in[4];
    const float* mp_wk = (const float*)d_in[5];
    const float* mp_wq = (const float*)d_in[6];
    const float* mp_wv = (const float*)d_in[7];
    const float* mp_ws = (const float*)d_in[8];
    const float* mp_g  = (const float*)d_in[9];
    const float* mp_b  = (const float*)d_in[10];
    const int N = in_sizes[0] / DIN;     // 50000
    const int E = in_sizes[1] / 2;       // 800000

    char* wsp = (char*)d_ws;
    size_t off = 0;
    auto alloc = [&](size_t bytes) {
        void* p = wsp + off;
        off = (off + bytes + 255) & ~(size_t)255;
        return p;
    };
    float* hA     = (float*)alloc((size_t)N * DIM * 4);
    float* hB     = (float*)alloc((size_t)N * DIM * 4);
    float* Kb     = (float*)alloc((size_t)N * DIM * 4);
    float* Qb     = (float*)alloc((size_t)N * DIM * 4);
    float* Vb     = (float*)alloc((size_t)N * DIM * 4);
    int*   counts = (int*)alloc((size_t)N * 4);
    int*   rp     = (int*)alloc((size_t)(N + 1) * 4);
    int*   cursor = (int*)alloc((size_t)N * 4);
    int*   bsums  = (int*)alloc(256);
    int*   boff   = (int*)alloc(256);
    int*   srcS   = (int*)alloc((size_t)E * 4);
    float* colsum = (float*)alloc(512);   // colsq contiguous right after
    float* colsq  = (float*)alloc(512);
    float* scale  = (float*)alloc(512);
    float* shift  = (float*)alloc(512);

    // --- CSR by dst (edge_index identical for both layers → build once)
    hipMemsetAsync(counts, 0, (size_t)N * 4, stream);
    hist_kernel<<<(E + 255) / 256, 256, 0, stream>>>(ei, counts, E);
    int G1 = (N + 1023) / 1024;
    scan1_kernel<<<G1, 1024, 0, stream>>>(counts, rp, bsums, N);
    scan2_kernel<<<1, 64, 0, stream>>>(bsums, boff, G1);
    scan3_kernel<<<G1, 1024, 0, stream>>>(counts, rp, cursor, boff, N, E);
    fill_kernel<<<(E + 255) / 256, 256, 0, stream>>>(ei, cursor, srcS, E);

    // --- pre layer: Linear -> BN -> ReLU -> L2norm
    pre_gemm_kernel<<<1024, 128, 0, stream>>>(x, pre_w, hA, N);
    hipMemsetAsync(colsum, 0, 1024, stream);   // colsum + colsq
    colstats_kernel<<<512, 128, 0, stream>>>(hA, colsum, colsq, N);
    scaleshift_kernel<<<1, 128, 0, stream>>>(colsum, colsq, pre_g, pre_b, scale, shift, 1.0f / N);
    finalize_kernel<<<(N + 3) / 4, 256, 0, stream>>>(hA, scale, shift, N);

    // --- message-passing layers
    float* hin = hA;
    for (int l = 0; l < 2; ++l) {
        float* hout = (l == 0) ? hB : (float*)d_out;
        const float* wk = mp_wk + (size_t)l * DIM * DIM;
        const float* wq = mp_wq + (size_t)l * DIM * DIM;
        const float* wv = mp_wv + (size_t)l * DIM * DIM;
        const float* ws = mp_ws + (size_t)l * DIM * DIM;
        dim3 g(8, (N + BM - 1) / BM);
        gemm4_kernel<<<g, 256, 0, stream>>>(hin, wk, wq, wv, ws, Kb, Qb, Vb, hout, N);
        aggregate_kernel<<<N, 128, 0, stream>>>(Kb, Qb, Vb, rp, srcS, hout, N);
        hipMemsetAsync(colsum, 0, 1024, stream);
        colstats_kernel<<<512, 128, 0, stream>>>(hout, colsum, colsq, N);
        scaleshift_kernel<<<1, 128, 0, stream>>>(colsum, colsq, mp_g + l * DIM, mp_b + l * DIM,
                                                 scale, shift, 1.0f / N);
        finalize_kernel<<<(N + 3) / 4, 256, 0, stream>>>(hout, scale, shift, N);
        hin = hout;
    }
}

// Round 2
// 771.283 us; speedup vs baseline: 1.0124x; 1.0124x over previous
//
#include <hip/hip_runtime.h>
#include <math.h>

#define DIM 128
#define DIN 20

// ---------------------------------------------------------------- CSR build
__global__ void hist_kernel(const int* __restrict__ ei, int* __restrict__ counts, int E) {
    int e = blockIdx.x * 256 + threadIdx.x;
    if (e < E) atomicAdd(&counts[ei[E + e]], 1);   // row 1 = dst
}

__global__ void scan1_kernel(const int* __restrict__ counts, int* __restrict__ incl,
                             int* __restrict__ blockSums, int N) {
    __shared__ int s[1024];
    int t = threadIdx.x;
    int i = blockIdx.x * 1024 + t;
    s[t] = (i < N) ? counts[i] : 0;
    __syncthreads();
    for (int off = 1; off < 1024; off <<= 1) {
        int x = (t >= off) ? s[t - off] : 0;
        __syncthreads();
        s[t] += x;
        __syncthreads();
    }
    if (i < N) incl[i] = s[t];
    if (t == 1023) blockSums[blockIdx.x] = s[1023];
}

__global__ void scan2_kernel(const int* __restrict__ blockSums, int* __restrict__ blockOff, int G) {
    int t = threadIdx.x;                 // 64 threads, G <= 64
    int v = (t < G) ? blockSums[t] : 0;
    int incl = v;
    #pragma unroll
    for (int off = 1; off < 64; off <<= 1) {
        int n = __shfl_up(incl, off);
        if (t >= off) incl += n;
    }
    if (t < G) blockOff[t] = incl - v;   // exclusive
}

__global__ void scan3_kernel(const int* __restrict__ counts, int* __restrict__ rp,
                             int* __restrict__ cursor, const int* __restrict__ blockOff,
                             int N, int E) {
    int i = blockIdx.x * 1024 + threadIdx.x;
    if (i < N) {
        int excl = rp[i] - counts[i] + blockOff[blockIdx.x];
        rp[i] = excl;
        cursor[i] = excl;
    }
    if (i == 0) rp[N] = E;
}

__global__ void fill_kernel(const int* __restrict__ ei, int* __restrict__ cursor,
                            int* __restrict__ srcS, int E) {
    int e = blockIdx.x * 256 + threadIdx.x;
    if (e >= E) return;
    int d = ei[E + e];
    int pos = atomicAdd(&cursor[d], 1);
    srcS[pos] = ei[e];                               // row 0 = src
}

// ---------------------------------------------------------------- pre GEMM  h = x @ pre_w   [N,20]x[20,128]
__global__ __launch_bounds__(128) void pre_gemm_kernel(const float* __restrict__ x,
                                                       const float* __restrict__ w,
                                                       float* __restrict__ h, int N) {
    __shared__ float ws_[DIN * DIM];
    __shared__ float xr[DIN];
    int tid = threadIdx.x;
    for (int i = tid; i < DIN * DIM; i += 128) ws_[i] = w[i];
    for (int row = blockIdx.x; row < N; row += gridDim.x) {
        __syncthreads();
        if (tid < DIN) xr[tid] = x[(size_t)row * DIN + tid];
        __syncthreads();
        float acc = 0.f;
        #pragma unroll
        for (int k = 0; k < DIN; ++k) acc = fmaf(xr[k], ws_[k * DIM + tid], acc);
        h[(size_t)row * DIM + tid] = acc;
    }
}

// ---------------------------------------------------------------- fused GEMM  [N,128] x [128,128], one weight per cb
// 128x128 block tile, 256 threads, 8x8 per-thread micro-tile (cols tx*4 and 64+tx*4).
#define BM 128
#define BKK 32
__global__ __launch_bounds__(256) void gemm4_kernel(
        const float* __restrict__ A,
        const float* __restrict__ Wk, const float* __restrict__ Wq,
        const float* __restrict__ Wv, const float* __restrict__ Wsp,
        float* __restrict__ K, float* __restrict__ QV, float* __restrict__ S, int N) {
    __shared__ float As[BKK][BM + 4];   // k-major (transposed), +4 pad
    __shared__ float Bs[BKK][DIM];
    int cb = blockIdx.x;                // 0:K 1:Q 2:V 3:S
    int row0 = blockIdx.y * BM;
    const float* W = (cb == 0) ? Wk : (cb == 1) ? Wq : (cb == 2) ? Wv : Wsp;
    float* O; int ldO;
    if (cb == 0)      { O = K;        ldO = 128; }
    else if (cb == 1) { O = QV;       ldO = 256; }
    else if (cb == 2) { O = QV + 128; ldO = 256; }
    else              { O = S;        ldO = 128; }
    int tid = threadIdx.x;
    int tx = tid & 15;                  // col groups: tx*4 and 64+tx*4
    int ty = tid >> 4;                  // rows ty*8 .. ty*8+7
    float acc[8][8] = {};
    for (int k0 = 0; k0 < DIM; k0 += BKK) {
        #pragma unroll
        for (int v = 0; v < 4; ++v) {   // A tile 128x32, transposed into LDS
            int lin = tid + v * 256;    // 0..1023
            int r = lin >> 3;           // 0..127
            int kc = (lin & 7) << 2;    // 0,4,..,28
            float4 a4 = make_float4(0.f, 0.f, 0.f, 0.f);
            if (row0 + r < N) a4 = *(const float4*)(A + (size_t)(row0 + r) * DIM + k0 + kc);
            As[kc + 0][r] = a4.x; As[kc + 1][r] = a4.y;
            As[kc + 2][r] = a4.z; As[kc + 3][r] = a4.w;
        }
        #pragma unroll
        for (int v = 0; v < 4; ++v) {   // B tile 32x128
            int lin = tid + v * 256;
            int r = lin >> 5;           // 0..31
            int c4 = (lin & 31) << 2;   // 0..124
            *(float4*)&Bs[r][c4] = *(const float4*)(W + (size_t)(k0 + r) * DIM + c4);
        }
        __syncthreads();
        #pragma unroll 8
        for (int k = 0; k < BKK; ++k) {
            float4 a0 = *(const float4*)&As[k][ty * 8];
            float4 a1 = *(const float4*)&As[k][ty * 8 + 4];
            float4 b0 = *(const float4*)&Bs[k][tx * 4];
            float4 b1 = *(const float4*)&Bs[k][64 + tx * 4];
            float ar[8] = {a0.x, a0.y, a0.z, a0.w, a1.x, a1.y, a1.z, a1.w};
            float br[8] = {b0.x, b0.y, b0.z, b0.w, b1.x, b1.y, b1.z, b1.w};
            #pragma unroll
            for (int i = 0; i < 8; ++i)
                #pragma unroll
                for (int j = 0; j < 8; ++j)
                    acc[i][j] = fmaf(ar[i], br[j], acc[i][j]);
        }
        __syncthreads();
    }
    #pragma unroll
    for (int i = 0; i < 8; ++i) {
        int r = row0 + ty * 8 + i;
        if (r < N) {
            *(float4*)(O + (size_t)r * ldO + tx * 4) =
                make_float4(acc[i][0], acc[i][1], acc[i][2], acc[i][3]);
            *(float4*)(O + (size_t)r * ldO + 64 + tx * 4) =
                make_float4(acc[i][4], acc[i][5], acc[i][6], acc[i][7]);
        }
    }
}

// ---------------------------------------------------------------- pull aggregation (CSR by dst)
__device__ __forceinline__ float sigf(float s) {
    return __builtin_amdgcn_rcpf(1.f + __expf(-s));
}

__global__ __launch_bounds__(128) void aggregate_kernel(
        const float* __restrict__ K, const float* __restrict__ QV,
        const int* __restrict__ rp, const int* __restrict__ srcS,
        float* __restrict__ out, int N) {
    int i = blockIdx.x;
    int c = threadIdx.x;
    size_t ib = (size_t)i * DIM;
    float kv = K[ib + c];
    int beg = rp[i], end = rp[i + 1];
    float a0 = 0.f, a1 = 0.f, a2 = 0.f, a3 = 0.f;
    int e = beg;
    for (; e + 4 <= end; e += 4) {
        int j0 = srcS[e], j1 = srcS[e + 1], j2 = srcS[e + 2], j3 = srcS[e + 3];
        const float* p0 = QV + (size_t)j0 * 256;
        const float* p1 = QV + (size_t)j1 * 256;
        const float* p2 = QV + (size_t)j2 * 256;
        const float* p3 = QV + (size_t)j3 * 256;
        float q0 = p0[c], q1 = p1[c], q2 = p2[c], q3 = p3[c];
        float v0 = p0[128 + c], v1 = p1[128 + c], v2 = p2[128 + c], v3 = p3[128 + c];
        a0 = fmaf(sigf(kv + q0), v0, a0);
        a1 = fmaf(sigf(kv + q1), v1, a1);
        a2 = fmaf(sigf(kv + q2), v2, a2);
        a3 = fmaf(sigf(kv + q3), v3, a3);
    }
    for (; e < end; ++e) {
        int j = srcS[e];
        const float* p = QV + (size_t)j * 256;
        a0 = fmaf(sigf(kv + p[c]), p[128 + c], a0);
    }
    out[ib + c] += (a0 + a1) + (a2 + a3);   // out pre-filled with h @ Ws
}

// ---------------------------------------------------------------- BN column stats
__global__ __launch_bounds__(128) void colstats_kernel(const float* __restrict__ h,
                                                       float* __restrict__ colsum,
                                                       float* __restrict__ colsq, int N) {
    int c = threadIdx.x;
    float s = 0.f, sq = 0.f;
    for (int r = blockIdx.x; r < N; r += gridDim.x) {
        float v = h[(size_t)r * DIM + c];
        s += v;
        sq = fmaf(v, v, sq);
    }
    atomicAdd(&colsum[c], s);
    atomicAdd(&colsq[c], sq);
}

__global__ void scaleshift_kernel(const float* __restrict__ colsum, const float* __restrict__ colsq,
                                  const float* __restrict__ gamma, const float* __restrict__ beta,
                                  float* __restrict__ scale, float* __restrict__ shift, float invN) {
    int c = threadIdx.x;
    float mu  = colsum[c] * invN;
    float var = colsq[c] * invN - mu * mu;
    float sc  = gamma[c] * rsqrtf(var + 1e-5f);
    scale[c] = sc;
    shift[c] = beta[c] - mu * sc;
}

// ---------------------------------------------------------------- BN apply + ReLU + row L2 norm (in place)
__global__ __launch_bounds__(256) void finalize_kernel(float* __restrict__ h,
                                                       const float* __restrict__ scale,
                                                       const float* __restrict__ shift, int N) {
    int row = blockIdx.x * 4 + (threadIdx.x >> 6);
    int lane = threadIdx.x & 63;
    if (row >= N) return;
    size_t base = (size_t)row * DIM;
    float y0 = fmaf(h[base + lane],      scale[lane],      shift[lane]);
    float y1 = fmaf(h[base + lane + 64], scale[lane + 64], shift[lane + 64]);
    y0 = fmaxf(y0, 0.f);
    y1 = fmaxf(y1, 0.f);
    float ss = y0 * y0 + y1 * y1;
    #pragma unroll
    for (int off = 32; off; off >>= 1) ss += __shfl_xor(ss, off);
    float inv = 1.0f / fmaxf(sqrtf(ss), 1e-12f);
    h[base + lane]      = y0 * inv;
    h[base + lane + 64] = y1 * inv;
}

// ---------------------------------------------------------------- launch
extern "C" void kernel_launch(void* const* d_in, const int* in_sizes, int n_in,
                              void* d_out, int out_size, void* d_ws, size_t ws_size,
                              hipStream_t stream) {
    const float* x     = (const float*)d_in[0];
    const int*   ei    = (const int*)d_in[1];
    const float* pre_w = (const float*)d_in[2];
    const float* pre_g = (const float*)d_in[3];
    const float* pre_b = (const float*)d_in[4];
    const float* mp_wk = (const float*)d_in[5];
    const float* mp_wq = (const float*)d_in[6];
    const float* mp_wv = (const float*)d_in[7];
    const float* mp_ws = (const float*)d_in[8];
    const float* mp_g  = (const float*)d_in[9];
    const float* mp_b  = (const float*)d_in[10];
    const int N = in_sizes[0] / DIN;     // 50000
    const int E = in_sizes[1] / 2;       // 800000

    char* wsp = (char*)d_ws;
    size_t off = 0;
    auto alloc = [&](size_t bytes) {
        void* p = wsp + off;
        off = (off + bytes + 255) & ~(size_t)255;
        return p;
    };
    float* hA     = (float*)alloc((size_t)N * DIM * 4);
    float* hB     = (float*)alloc((size_t)N * DIM * 4);
    float* Kb     = (float*)alloc((size_t)N * DIM * 4);
    float* QVb    = (float*)alloc((size_t)N * DIM * 8);   // Q|V interleaved, row = 256 floats
    int*   counts = (int*)alloc((size_t)N * 4);
    int*   rp     = (int*)alloc((size_t)(N + 1) * 4);
    int*   cursor = (int*)alloc((size_t)N * 4);
    int*   bsums  = (int*)alloc(256);
    int*   boff   = (int*)alloc(256);
    int*   srcS   = (int*)alloc((size_t)E * 4);
    float* colsum = (float*)alloc(512);   // colsq contiguous right after
    float* colsq  = (float*)alloc(512);
    float* scale  = (float*)alloc(512);
    float* shift  = (float*)alloc(512);

    // --- CSR by dst (edge_index identical for both layers → build once)
    hipMemsetAsync(counts, 0, (size_t)N * 4, stream);
    hist_kernel<<<(E + 255) / 256, 256, 0, stream>>>(ei, counts, E);
    int G1 = (N + 1023) / 1024;
    scan1_kernel<<<G1, 1024, 0, stream>>>(counts, rp, bsums, N);
    scan2_kernel<<<1, 64, 0, stream>>>(bsums, boff, G1);
    scan3_kernel<<<G1, 1024, 0, stream>>>(counts, rp, cursor, boff, N, E);
    fill_kernel<<<(E + 255) / 256, 256, 0, stream>>>(ei, cursor, srcS, E);

    // --- pre layer: Linear -> BN -> ReLU -> L2norm
    pre_gemm_kernel<<<1024, 128, 0, stream>>>(x, pre_w, hA, N);
    hipMemsetAsync(colsum, 0, 1024, stream);   // colsum + colsq
    colstats_kernel<<<512, 128, 0, stream>>>(hA, colsum, colsq, N);
    scaleshift_kernel<<<1, 128, 0, stream>>>(colsum, colsq, pre_g, pre_b, scale, shift, 1.0f / N);
    finalize_kernel<<<(N + 3) / 4, 256, 0, stream>>>(hA, scale, shift, N);

    // --- message-passing layers
    float* hin = hA;
    for (int l = 0; l < 2; ++l) {
        float* hout = (l == 0) ? hB : (float*)d_out;
        const float* wk = mp_wk + (size_t)l * DIM * DIM;
        const float* wq = mp_wq + (size_t)l * DIM * DIM;
        const float* wv = mp_wv + (size_t)l * DIM * DIM;
        const float* ws = mp_ws + (size_t)l * DIM * DIM;
        dim3 g(4, (N + BM - 1) / BM);
        gemm4_kernel<<<g, 256, 0, stream>>>(hin, wk, wq, wv, ws, Kb, QVb, hout, N);
        aggregate_kernel<<<N, 128, 0, stream>>>(Kb, QVb, rp, srcS, hout, N);
        hipMemsetAsync(colsum, 0, 1024, stream);
        colstats_kernel<<<512, 128, 0, stream>>>(hout, colsum, colsq, N);
        scaleshift_kernel<<<1, 128, 0, stream>>>(colsum, colsq, mp_g + l * DIM, mp_b + l * DIM,
                                                 scale, shift, 1.0f / N);
        finalize_kernel<<<(N + 3) / 4, 256, 0, stream>>>(hout, scale, shift, N);
        hin = hout;
    }
}

// Round 3
// 573.583 us; speedup vs baseline: 1.3614x; 1.3447x over previous
//
#include <hip/hip_runtime.h>
#include <math.h>

#define DIM 128
#define DIN 20

typedef __attribute__((ext_vector_type(8))) short bf16x8;
typedef __attribute__((ext_vector_type(4))) float f32x4;

__device__ __forceinline__ unsigned short f2bf(float x) {
    unsigned u = __float_as_uint(x);
    u = (u + 0x7FFF + ((u >> 16) & 1)) >> 16;   // RNE
    return (unsigned short)u;
}
__device__ __forceinline__ float sigf(float s) {
    return __builtin_amdgcn_rcpf(1.f + __expf(-s));
}

// ---------------------------------------------------------------- CSR build
__global__ void hist_kernel(const int* __restrict__ ei, int* __restrict__ counts, int E) {
    int e = blockIdx.x * 256 + threadIdx.x;
    if (e < E) atomicAdd(&counts[ei[E + e]], 1);   // row 1 = dst
}

__global__ void scan1_kernel(const int* __restrict__ counts, int* __restrict__ incl,
                             int* __restrict__ blockSums, int N) {
    __shared__ int s[1024];
    int t = threadIdx.x;
    int i = blockIdx.x * 1024 + t;
    s[t] = (i < N) ? counts[i] : 0;
    __syncthreads();
    for (int off = 1; off < 1024; off <<= 1) {
        int x = (t >= off) ? s[t - off] : 0;
        __syncthreads();
        s[t] += x;
        __syncthreads();
    }
    if (i < N) incl[i] = s[t];
    if (t == 1023) blockSums[blockIdx.x] = s[1023];
}

__global__ void scan2_kernel(const int* __restrict__ blockSums, int* __restrict__ blockOff, int G) {
    int t = threadIdx.x;                 // 64 threads, G <= 64
    int v = (t < G) ? blockSums[t] : 0;
    int incl = v;
    #pragma unroll
    for (int off = 1; off < 64; off <<= 1) {
        int n = __shfl_up(incl, off);
        if (t >= off) incl += n;
    }
    if (t < G) blockOff[t] = incl - v;   // exclusive
}

__global__ void scan3_kernel(const int* __restrict__ counts, int* __restrict__ rp,
                             int* __restrict__ cursor, const int* __restrict__ blockOff,
                             int N, int E) {
    int i = blockIdx.x * 1024 + threadIdx.x;
    if (i < N) {
        int excl = rp[i] - counts[i] + blockOff[blockIdx.x];
        rp[i] = excl;
        cursor[i] = excl;
    }
    if (i == 0) rp[N] = E;
}

__global__ void fill_kernel(const int* __restrict__ ei, int* __restrict__ cursor,
                            int* __restrict__ srcS, int E) {
    int e = blockIdx.x * 256 + threadIdx.x;
    if (e >= E) return;
    int d = ei[E + e];
    int pos = atomicAdd(&cursor[d], 1);
    srcS[pos] = ei[e];                               // row 0 = src
}

// ---------------------------------------------------------------- weight convert: W[k][c] f32 -> Wt[c][k] bf16
// grid.x = 8 (layer*4 + weight), weights ordered K,Q,V,S
__global__ __launch_bounds__(128) void wconv_kernel(const float* __restrict__ wk,
                                                    const float* __restrict__ wq,
                                                    const float* __restrict__ wv,
                                                    const float* __restrict__ ws,
                                                    unsigned short* __restrict__ wt) {
    int l = blockIdx.x >> 2, w = blockIdx.x & 3;
    const float* src = (w == 0 ? wk : w == 1 ? wq : w == 2 ? wv : ws) + (size_t)l * DIM * DIM;
    unsigned short* dst = wt + (size_t)blockIdx.x * DIM * DIM;
    int c = threadIdx.x;
    for (int k = 0; k < DIM; ++k) dst[c * DIM + k] = f2bf(src[k * DIM + c]);
}

// ---------------------------------------------------------------- pre GEMM  h = x @ pre_w   [N,20]x[20,128]
__global__ __launch_bounds__(128) void pre_gemm_kernel(const float* __restrict__ x,
                                                       const float* __restrict__ w,
                                                       float* __restrict__ h, int N) {
    __shared__ float ws_[DIN * DIM];
    __shared__ float xr[DIN];
    int tid = threadIdx.x;
    for (int i = tid; i < DIN * DIM; i += 128) ws_[i] = w[i];
    for (int row = blockIdx.x; row < N; row += gridDim.x) {
        __syncthreads();
        if (tid < DIN) xr[tid] = x[(size_t)row * DIN + tid];
        __syncthreads();
        float acc = 0.f;
        #pragma unroll
        for (int k = 0; k < DIN; ++k) acc = fmaf(xr[k], ws_[k * DIM + tid], acc);
        h[(size_t)row * DIM + tid] = acc;
    }
}

// ---------------------------------------------------------------- MFMA GEMM  [N,128](bf16) x Wt[128,128](bf16)
// grid (4 weights, ceil(N/128)); 256 threads = 4 waves; wave = 64 rows x 64 cols.
// A tile in XOR-swizzled LDS; B fragments in registers from global Wt (hot in L2).
__global__ __launch_bounds__(256) void gemm_mfma_kernel(
        const unsigned short* __restrict__ A,    // [N][128] bf16
        const unsigned short* __restrict__ Wt,   // [4][128][128] bf16, col-major-k, this layer
        float* __restrict__ K, unsigned short* __restrict__ QV,
        float* __restrict__ S, int N) {
    __shared__ unsigned short Asw[DIM * DIM];    // 32 KB
    int cb = blockIdx.x;                         // 0:K 1:Q 2:V 3:S
    int row0 = blockIdx.y * 128;
    int tid = threadIdx.x;

    // stage A (128 rows x 256B), 16B granules, swizzled: byte = r*256 + ((ch*16) ^ ((r&7)<<4))
    #pragma unroll
    for (int i = 0; i < 8; ++i) {
        int g = tid + i * 256;                   // 0..2047
        int r = g >> 4, ch = g & 15;
        int row = row0 + r;
        bf16x8 v = {0, 0, 0, 0, 0, 0, 0, 0};
        if (row < N) v = *(const bf16x8*)(A + (size_t)row * DIM + ch * 8);
        int dst = r * 256 + ((ch * 16) ^ ((r & 7) << 4));
        *(bf16x8*)((char*)Asw + dst) = v;
    }

    const unsigned short* W = Wt + (size_t)cb * DIM * DIM;
    int w = tid >> 6, l = tid & 63;
    int r0 = (w >> 1) * 64, c0 = (w & 1) * 64;
    int lr = l & 15, lk = l >> 4;

    bf16x8 b[4][4];                              // [nf][ks]
    #pragma unroll
    for (int nf = 0; nf < 4; ++nf)
        #pragma unroll
        for (int ks = 0; ks < 4; ++ks) {
            int col = c0 + nf * 16 + lr;
            int k = ks * 32 + lk * 8;
            b[nf][ks] = *(const bf16x8*)(W + (size_t)col * DIM + k);
        }
    __syncthreads();

    f32x4 acc[4][4] = {};                        // [mf][nf]
    #pragma unroll
    for (int mf = 0; mf < 4; ++mf) {
        bf16x8 a[4];
        #pragma unroll
        for (int ks = 0; ks < 4; ++ks) {
            int row = r0 + mf * 16 + lr;
            int kb = ks * 64 + lk * 16;
            int off = row * 256 + (kb ^ ((row & 7) << 4));
            a[ks] = *(const bf16x8*)((char*)Asw + off);
        }
        #pragma unroll
        for (int nf = 0; nf < 4; ++nf)
            #pragma unroll
            for (int ks = 0; ks < 4; ++ks)
                acc[mf][nf] = __builtin_amdgcn_mfma_f32_16x16x32_bf16(
                    a[ks], b[nf][ks], acc[mf][nf], 0, 0, 0);
    }

    // epilogue: D row = (lane>>4)*4 + reg, col = lane&15  [m89-verified]
    #pragma unroll
    for (int mf = 0; mf < 4; ++mf)
        #pragma unroll
        for (int nf = 0; nf < 4; ++nf)
            #pragma unroll
            for (int j = 0; j < 4; ++j) {
                int row = row0 + r0 + mf * 16 + lk * 4 + j;
                int col = c0 + nf * 16 + lr;
                if (row < N) {
                    float v = acc[mf][nf][j];
                    if (cb == 0)      K[(size_t)row * DIM + col] = v;
                    else if (cb == 1) QV[(size_t)row * 256 + col] = f2bf(v);
                    else if (cb == 2) QV[(size_t)row * 256 + 128 + col] = f2bf(v);
                    else              S[(size_t)row * DIM + col] = v;
                }
            }
}

// ---------------------------------------------------------------- pull aggregation (CSR by dst), bf16 QV
// 1 wave per dst node; thread t owns cols {2t, 2t+1}; QV row = 128 uints (Q 0..63 | V 64..127).
__global__ __launch_bounds__(64) void aggregate_kernel(
        const float* __restrict__ K, const unsigned int* __restrict__ QV,
        const int* __restrict__ rp, const int* __restrict__ srcS,
        float* __restrict__ out, int N) {
    int i = blockIdx.x;
    int t = threadIdx.x;
    float2 kv = *(const float2*)(K + (size_t)i * DIM + 2 * t);
    int beg = rp[i], end = rp[i + 1];
    float a0x = 0, a0y = 0, a1x = 0, a1y = 0, a2x = 0, a2y = 0, a3x = 0, a3y = 0;
    int e = beg;
    for (; e + 4 <= end; e += 4) {
        int j0 = srcS[e], j1 = srcS[e + 1], j2 = srcS[e + 2], j3 = srcS[e + 3];
        const unsigned* p0 = QV + (size_t)j0 * 128;
        const unsigned* p1 = QV + (size_t)j1 * 128;
        const unsigned* p2 = QV + (size_t)j2 * 128;
        const unsigned* p3 = QV + (size_t)j3 * 128;
        unsigned q0 = p0[t], q1 = p1[t], q2 = p2[t], q3 = p3[t];
        unsigned v0 = p0[64 + t], v1 = p1[64 + t], v2 = p2[64 + t], v3 = p3[64 + t];
        a0x = fmaf(sigf(kv.x + __uint_as_float(q0 << 16)),          __uint_as_float(v0 << 16),          a0x);
        a0y = fmaf(sigf(kv.y + __uint_as_float(q0 & 0xffff0000u)),  __uint_as_float(v0 & 0xffff0000u),  a0y);
        a1x = fmaf(sigf(kv.x + __uint_as_float(q1 << 16)),          __uint_as_float(v1 << 16),          a1x);
        a1y = fmaf(sigf(kv.y + __uint_as_float(q1 & 0xffff0000u)),  __uint_as_float(v1 & 0xffff0000u),  a1y);
        a2x = fmaf(sigf(kv.x + __uint_as_float(q2 << 16)),          __uint_as_float(v2 << 16),          a2x);
        a2y = fmaf(sigf(kv.y + __uint_as_float(q2 & 0xffff0000u)),  __uint_as_float(v2 & 0xffff0000u),  a2y);
        a3x = fmaf(sigf(kv.x + __uint_as_float(q3 << 16)),          __uint_as_float(v3 << 16),          a3x);
        a3y = fmaf(sigf(kv.y + __uint_as_float(q3 & 0xffff0000u)),  __uint_as_float(v3 & 0xffff0000u),  a3y);
    }
    for (; e < end; ++e) {
        int j = srcS[e];
        const unsigned* p = QV + (size_t)j * 128;
        unsigned q = p[t], v = p[64 + t];
        a0x = fmaf(sigf(kv.x + __uint_as_float(q << 16)),         __uint_as_float(v << 16),         a0x);
        a0y = fmaf(sigf(kv.y + __uint_as_float(q & 0xffff0000u)), __uint_as_float(v & 0xffff0000u), a0y);
    }
    float2 o = *(float2*)(out + (size_t)i * DIM + 2 * t);
    o.x += (a0x + a1x) + (a2x + a3x);
    o.y += (a0y + a1y) + (a2y + a3y);
    *(float2*)(out + (size_t)i * DIM + 2 * t) = o;
}

// ---------------------------------------------------------------- BN column stats
__global__ __launch_bounds__(128) void colstats_kernel(const float* __restrict__ h,
                                                       float* __restrict__ colsum,
                                                       float* __restrict__ colsq, int N) {
    int c = threadIdx.x;
    float s = 0.f, sq = 0.f;
    for (int r = blockIdx.x; r < N; r += gridDim.x) {
        float v = h[(size_t)r * DIM + c];
        s += v;
        sq = fmaf(v, v, sq);
    }
    atomicAdd(&colsum[c], s);
    atomicAdd(&colsq[c], sq);
}

// ---------------------------------------------------------------- BN + ReLU + row L2 norm (+ optional bf16 out)
__global__ __launch_bounds__(256) void finalize_kernel(
        const float* __restrict__ h, float* __restrict__ of32, unsigned short* __restrict__ ob16,
        const float* __restrict__ colsum, const float* __restrict__ colsq,
        const float* __restrict__ gamma, const float* __restrict__ beta,
        float invN, int N) {
    int row = blockIdx.x * 4 + (threadIdx.x >> 6);
    int lane = threadIdx.x & 63;
    if (row >= N) return;
    int c0 = lane, c1 = lane + 64;
    float mu0 = colsum[c0] * invN;
    float var0 = colsq[c0] * invN - mu0 * mu0;
    float sc0 = gamma[c0] * rsqrtf(var0 + 1e-5f);
    float sh0 = beta[c0] - mu0 * sc0;
    float mu1 = colsum[c1] * invN;
    float var1 = colsq[c1] * invN - mu1 * mu1;
    float sc1 = gamma[c1] * rsqrtf(var1 + 1e-5f);
    float sh1 = beta[c1] - mu1 * sc1;
    size_t base = (size_t)row * DIM;
    float y0 = fmaxf(fmaf(h[base + c0], sc0, sh0), 0.f);
    float y1 = fmaxf(fmaf(h[base + c1], sc1, sh1), 0.f);
    float ss = y0 * y0 + y1 * y1;
    #pragma unroll
    for (int off = 32; off; off >>= 1) ss += __shfl_xor(ss, off);
    float inv = 1.0f / fmaxf(sqrtf(ss), 1e-12f);
    y0 *= inv; y1 *= inv;
    if (of32) { of32[base + c0] = y0; of32[base + c1] = y1; }
    if (ob16) { ob16[base + c0] = f2bf(y0); ob16[base + c1] = f2bf(y1); }
}

// ---------------------------------------------------------------- launch
extern "C" void kernel_launch(void* const* d_in, const int* in_sizes, int n_in,
                              void* d_out, int out_size, void* d_ws, size_t ws_size,
                              hipStream_t stream) {
    const float* x     = (const float*)d_in[0];
    const int*   ei    = (const int*)d_in[1];
    const float* pre_w = (const float*)d_in[2];
    const float* pre_g = (const float*)d_in[3];
    const float* pre_b = (const float*)d_in[4];
    const float* mp_wk = (const float*)d_in[5];
    const float* mp_wq = (const float*)d_in[6];
    const float* mp_wv = (const float*)d_in[7];
    const float* mp_ws = (const float*)d_in[8];
    const float* mp_g  = (const float*)d_in[9];
    const float* mp_b  = (const float*)d_in[10];
    const int N = in_sizes[0] / DIN;     // 50000
    const int E = in_sizes[1] / 2;       // 800000

    char* wsp = (char*)d_ws;
    size_t off = 0;
    auto alloc = [&](size_t bytes) {
        void* p = wsp + off;
        off = (off + bytes + 255) & ~(size_t)255;
        return p;
    };
    float*          hA   = (float*)alloc((size_t)N * DIM * 4);
    float*          hB   = (float*)alloc((size_t)N * DIM * 4);
    float*          Kb   = (float*)alloc((size_t)N * DIM * 4);
    unsigned short* QVb  = (unsigned short*)alloc((size_t)N * 256 * 2);  // Q|V bf16, row = 512B
    unsigned short* hbf  = (unsigned short*)alloc((size_t)N * DIM * 2);  // gemm input
    unsigned short* wt   = (unsigned short*)alloc((size_t)8 * DIM * DIM * 2);
    int*   counts = (int*)alloc((size_t)N * 4);
    int*   rp     = (int*)alloc((size_t)(N + 1) * 4);
    int*   cursor = (int*)alloc((size_t)N * 4);
    int*   bsums  = (int*)alloc(256);
    int*   boff   = (int*)alloc(256);
    int*   srcS   = (int*)alloc((size_t)E * 4);
    float* colsum = (float*)alloc(512);   // colsq contiguous right after
    float* colsq  = (float*)alloc(512);

    // --- CSR by dst (same edges both layers → build once per call)
    hipMemsetAsync(counts, 0, (size_t)N * 4, stream);
    hist_kernel<<<(E + 255) / 256, 256, 0, stream>>>(ei, counts, E);
    int G1 = (N + 1023) / 1024;
    scan1_kernel<<<G1, 1024, 0, stream>>>(counts, rp, bsums, N);
    scan2_kernel<<<1, 64, 0, stream>>>(bsums, boff, G1);
    scan3_kernel<<<G1, 1024, 0, stream>>>(counts, rp, cursor, boff, N, E);
    fill_kernel<<<(E + 255) / 256, 256, 0, stream>>>(ei, cursor, srcS, E);

    // --- weights -> bf16 transposed
    wconv_kernel<<<8, 128, 0, stream>>>(mp_wk, mp_wq, mp_wv, mp_ws, wt);

    // --- pre layer: Linear -> BN -> ReLU -> L2norm -> bf16
    pre_gemm_kernel<<<1024, 128, 0, stream>>>(x, pre_w, hA, N);
    hipMemsetAsync(colsum, 0, 1024, stream);   // colsum + colsq
    colstats_kernel<<<512, 128, 0, stream>>>(hA, colsum, colsq, N);
    finalize_kernel<<<(N + 3) / 4, 256, 0, stream>>>(hA, nullptr, hbf,
                                                     colsum, colsq, pre_g, pre_b, 1.0f / N, N);

    // --- message-passing layers
    for (int l = 0; l < 2; ++l) {
        float* hout = (l == 0) ? hB : (float*)d_out;
        dim3 g(4, (N + 127) / 128);
        gemm_mfma_kernel<<<g, 256, 0, stream>>>(hbf, wt + (size_t)l * 4 * DIM * DIM,
                                                Kb, QVb, hout, N);
        aggregate_kernel<<<N, 64, 0, stream>>>(Kb, (const unsigned int*)QVb, rp, srcS, hout, N);
        hipMemsetAsync(colsum, 0, 1024, stream);
        colstats_kernel<<<512, 128, 0, stream>>>(hout, colsum, colsq, N);
        finalize_kernel<<<(N + 3) / 4, 256, 0, stream>>>(
            hout, (l == 1) ? hout : nullptr, (l == 0) ? hbf : nullptr,
            colsum, colsq, mp_g + l * DIM, mp_b + l * DIM, 1.0f / N, N);
    }
}

// Round 4
// 556.356 us; speedup vs baseline: 1.4036x; 1.0310x over previous
//
#include <hip/hip_runtime.h>
#include <math.h>

#define DIM 128
#define DIN 20

typedef __attribute__((ext_vector_type(8))) short bf16x8;
typedef __attribute__((ext_vector_type(4))) float f32x4;

__device__ __forceinline__ unsigned short f2bf(float x) {
    unsigned u = __float_as_uint(x);
    u = (u + 0x7FFF + ((u >> 16) & 1)) >> 16;   // RNE
    return (unsigned short)u;
}
__device__ __forceinline__ float sigf(float s) {
    return __builtin_amdgcn_rcpf(1.f + __expf(-s));
}
__device__ __forceinline__ float bflo(unsigned u) { return __uint_as_float(u << 16); }
__device__ __forceinline__ float bfhi(unsigned u) { return __uint_as_float(u & 0xffff0000u); }

// ---------------------------------------------------------------- CSR build
__global__ void hist_kernel(const int* __restrict__ ei, int* __restrict__ counts, int E) {
    int e = blockIdx.x * 256 + threadIdx.x;
    if (e < E) atomicAdd(&counts[ei[E + e]], 1);   // row 1 = dst
}

__global__ void scan1_kernel(const int* __restrict__ counts, int* __restrict__ incl,
                             int* __restrict__ blockSums, int N) {
    __shared__ int s[1024];
    int t = threadIdx.x;
    int i = blockIdx.x * 1024 + t;
    s[t] = (i < N) ? counts[i] : 0;
    __syncthreads();
    for (int off = 1; off < 1024; off <<= 1) {
        int x = (t >= off) ? s[t - off] : 0;
        __syncthreads();
        s[t] += x;
        __syncthreads();
    }
    if (i < N) incl[i] = s[t];
    if (t == 1023) blockSums[blockIdx.x] = s[1023];
}

__global__ void scan2_kernel(const int* __restrict__ blockSums, int* __restrict__ blockOff, int G) {
    int t = threadIdx.x;                 // 64 threads, G <= 64
    int v = (t < G) ? blockSums[t] : 0;
    int incl = v;
    #pragma unroll
    for (int off = 1; off < 64; off <<= 1) {
        int n = __shfl_up(incl, off);
        if (t >= off) incl += n;
    }
    if (t < G) blockOff[t] = incl - v;   // exclusive
}

__global__ void scan3_kernel(const int* __restrict__ counts, int* __restrict__ rp,
                             int* __restrict__ cursor, const int* __restrict__ blockOff,
                             int N, int E) {
    int i = blockIdx.x * 1024 + threadIdx.x;
    if (i < N) {
        int excl = rp[i] - counts[i] + blockOff[blockIdx.x];
        rp[i] = excl;
        cursor[i] = excl;
    }
    if (i == 0) rp[N] = E;
}

__global__ void fill_kernel(const int* __restrict__ ei, int* __restrict__ cursor,
                            int* __restrict__ srcS, int E) {
    int e = blockIdx.x * 256 + threadIdx.x;
    if (e >= E) return;
    int d = ei[E + e];
    int pos = atomicAdd(&cursor[d], 1);
    srcS[pos] = ei[e];                               // row 0 = src
}

// ---------------------------------------------------------------- weight convert: W[k][c] f32 -> Wt[c][k] bf16
__global__ __launch_bounds__(128) void wconv_kernel(const float* __restrict__ wk,
                                                    const float* __restrict__ wq,
                                                    const float* __restrict__ wv,
                                                    const float* __restrict__ ws,
                                                    unsigned short* __restrict__ wt) {
    int l = blockIdx.x >> 2, w = blockIdx.x & 3;
    const float* src = (w == 0 ? wk : w == 1 ? wq : w == 2 ? wv : ws) + (size_t)l * DIM * DIM;
    unsigned short* dst = wt + (size_t)blockIdx.x * DIM * DIM;
    int c = threadIdx.x;
    for (int k = 0; k < DIM; ++k) dst[c * DIM + k] = f2bf(src[k * DIM + c]);
}

// ---------------------------------------------------------------- pre GEMM  h = x @ pre_w   [N,20]x[20,128]
__global__ __launch_bounds__(128) void pre_gemm_kernel(const float* __restrict__ x,
                                                       const float* __restrict__ w,
                                                       float* __restrict__ h, int N) {
    __shared__ float ws_[DIN * DIM];
    __shared__ float xr[4][DIN];
    int tid = threadIdx.x;
    for (int i = tid; i < DIN * DIM; i += 128) ws_[i] = w[i];
    for (int r0 = blockIdx.x * 4; r0 < N; r0 += gridDim.x * 4) {
        __syncthreads();
        if (tid < 4 * DIN) {
            int rr = tid / DIN, kk = tid % DIN;
            if (r0 + rr < N) xr[rr][kk] = x[(size_t)(r0 + rr) * DIN + kk];
        }
        __syncthreads();
        #pragma unroll
        for (int rr = 0; rr < 4; ++rr) {
            int row = r0 + rr;
            if (row >= N) break;
            float acc = 0.f;
            #pragma unroll
            for (int k = 0; k < DIN; ++k) acc = fmaf(xr[rr][k], ws_[k * DIM + tid], acc);
            h[(size_t)row * DIM + tid] = acc;
        }
    }
}

// ---------------------------------------------------------------- MFMA GEMM, swapped operands
// One block per 64-row tile; computes all 4 weights (K,Q,V,S). 256 thr = 4 waves,
// wave w covers rows 0..63 x cols w*32..w*32+31. mfma(W_frag, act_frag) so each
// lane holds 1 output row x 4 consecutive cols -> vectorized stores.
#define GBM 64
__global__ __launch_bounds__(256) void gemm_mfma_kernel(
        const unsigned short* __restrict__ A,    // [N][128] bf16
        const unsigned short* __restrict__ Wt,   // [4][128][128] bf16 (col-major k), this layer
        float* __restrict__ K, unsigned int* __restrict__ QV,
        float* __restrict__ S, int N) {
    __shared__ unsigned short Asw[GBM * DIM];    // 16 KB, swizzled
    int row0 = blockIdx.x * GBM;
    int tid = threadIdx.x;

    // stage A 64x128 bf16 in 16B granules: byte = r*256 + ((ch*16) ^ ((r&7)<<4))
    #pragma unroll
    for (int i = 0; i < 4; ++i) {
        int g = tid + i * 256;                   // 0..1023
        int r = g >> 4, ch = g & 15;
        int row = row0 + r;
        bf16x8 v = {0, 0, 0, 0, 0, 0, 0, 0};
        if (row < N) v = *(const bf16x8*)(A + (size_t)row * DIM + ch * 8);
        int dst = r * 256 + ((ch * 16) ^ ((r & 7) << 4));
        *(bf16x8*)((char*)Asw + dst) = v;
    }
    __syncthreads();

    int w = tid >> 6, l = tid & 63;
    int c0 = w * 32;
    int lj = l & 15, lg = l >> 4;

    // act frags (B operand): row = mf*16+lj, k = ks*32+lg*8 — reused for all 4 weights
    bf16x8 act[4][4];
    #pragma unroll
    for (int mf = 0; mf < 4; ++mf) {
        int r = mf * 16 + lj;
        #pragma unroll
        for (int ks = 0; ks < 4; ++ks) {
            int off = r * 256 + ((ks * 64 + lg * 16) ^ ((r & 7) << 4));
            act[mf][ks] = *(const bf16x8*)((char*)Asw + off);
        }
    }

    #pragma unroll
    for (int wgt = 0; wgt < 4; ++wgt) {          // 0:K 1:Q 2:V 3:S
        const unsigned short* W = Wt + (size_t)wgt * DIM * DIM;
        bf16x8 wf[2][4];                         // (A operand): col = c0+nf*16+lj, k = ks*32+lg*8
        #pragma unroll
        for (int nf = 0; nf < 2; ++nf)
            #pragma unroll
            for (int ks = 0; ks < 4; ++ks)
                wf[nf][ks] = *(const bf16x8*)(W + (size_t)(c0 + nf * 16 + lj) * DIM + ks * 32 + lg * 8);
        f32x4 acc[4][2] = {};
        #pragma unroll
        for (int mf = 0; mf < 4; ++mf)
            #pragma unroll
            for (int nf = 0; nf < 2; ++nf)
                #pragma unroll
                for (int ks = 0; ks < 4; ++ks)
                    acc[mf][nf] = __builtin_amdgcn_mfma_f32_16x16x32_bf16(
                        wf[nf][ks], act[mf][ks], acc[mf][nf], 0, 0, 0);
        // lane holds: row = row0 + mf*16 + lj ; cols = c0 + nf*16 + lg*4 + (0..3)
        #pragma unroll
        for (int mf = 0; mf < 4; ++mf) {
            int row = row0 + mf * 16 + lj;
            if (row < N) {
                #pragma unroll
                for (int nf = 0; nf < 2; ++nf) {
                    int col = c0 + nf * 16 + lg * 4;
                    f32x4 v = acc[mf][nf];
                    if (wgt == 0) {
                        *(f32x4*)(K + (size_t)row * DIM + col) = v;
                    } else if (wgt == 3) {
                        *(f32x4*)(S + (size_t)row * DIM + col) = v;
                    } else {
                        unsigned p0 = ((unsigned)f2bf(v[1]) << 16) | f2bf(v[0]);
                        unsigned p1 = ((unsigned)f2bf(v[3]) << 16) | f2bf(v[2]);
                        unsigned* U = QV + (size_t)row * 128;
                        // interleaved: U[2m]=Q pair m, U[2m+1]=V pair m  (m = col/2)
                        if (wgt == 1) { U[col]     = p0; U[col + 2] = p1; }
                        else          { U[col + 1] = p0; U[col + 3] = p1; }
                    }
                }
            }
        }
    }
}

// ---------------------------------------------------------------- pull aggregation (CSR by dst)
// 1 wave per dst; thread t owns cols {2t,2t+1}; per edge one uint2 = {Qpair, Vpair}.
__global__ __launch_bounds__(64) void aggregate_kernel(
        const float* __restrict__ K, const unsigned int* __restrict__ QV,
        const int* __restrict__ rp, const int* __restrict__ srcS,
        float* __restrict__ out, int N) {
    int i = blockIdx.x;
    int t = threadIdx.x;
    float2 kv = *(const float2*)(K + (size_t)i * DIM + 2 * t);
    int beg = rp[i], end = rp[i + 1];
    float a0x = 0, a0y = 0, a1x = 0, a1y = 0, a2x = 0, a2y = 0, a3x = 0, a3y = 0;
    int e = beg;
    for (; e + 4 <= end; e += 4) {
        int j0 = srcS[e], j1 = srcS[e + 1], j2 = srcS[e + 2], j3 = srcS[e + 3];
        uint2 u0 = *(const uint2*)(QV + (size_t)j0 * 128 + 2 * t);
        uint2 u1 = *(const uint2*)(QV + (size_t)j1 * 128 + 2 * t);
        uint2 u2 = *(const uint2*)(QV + (size_t)j2 * 128 + 2 * t);
        uint2 u3 = *(const uint2*)(QV + (size_t)j3 * 128 + 2 * t);
        a0x = fmaf(sigf(kv.x + bflo(u0.x)), bflo(u0.y), a0x);
        a0y = fmaf(sigf(kv.y + bfhi(u0.x)), bfhi(u0.y), a0y);
        a1x = fmaf(sigf(kv.x + bflo(u1.x)), bflo(u1.y), a1x);
        a1y = fmaf(sigf(kv.y + bfhi(u1.x)), bfhi(u1.y), a1y);
        a2x = fmaf(sigf(kv.x + bflo(u2.x)), bflo(u2.y), a2x);
        a2y = fmaf(sigf(kv.y + bfhi(u2.x)), bfhi(u2.y), a2y);
        a3x = fmaf(sigf(kv.x + bflo(u3.x)), bflo(u3.y), a3x);
        a3y = fmaf(sigf(kv.y + bfhi(u3.x)), bfhi(u3.y), a3y);
    }
    for (; e < end; ++e) {
        int j = srcS[e];
        uint2 u = *(const uint2*)(QV + (size_t)j * 128 + 2 * t);
        a0x = fmaf(sigf(kv.x + bflo(u.x)), bflo(u.y), a0x);
        a0y = fmaf(sigf(kv.y + bfhi(u.x)), bfhi(u.y), a0y);
    }
    float2 o = *(float2*)(out + (size_t)i * DIM + 2 * t);
    o.x += (a0x + a1x) + (a2x + a3x);
    o.y += (a0y + a1y) + (a2y + a3y);
    *(float2*)(out + (size_t)i * DIM + 2 * t) = o;
}

// ---------------------------------------------------------------- BN column stats
__global__ __launch_bounds__(128) void colstats_kernel(const float* __restrict__ h,
                                                       float* __restrict__ colsum,
                                                       float* __restrict__ colsq, int N) {
    int c = threadIdx.x;
    float s = 0.f, sq = 0.f;
    for (int r = blockIdx.x; r < N; r += gridDim.x) {
        float v = h[(size_t)r * DIM + c];
        s += v;
        sq = fmaf(v, v, sq);
    }
    atomicAdd(&colsum[c], s);
    atomicAdd(&colsq[c], sq);
}

// ---------------------------------------------------------------- BN + ReLU + row L2 norm (+ optional bf16 out)
__global__ __launch_bounds__(256) void finalize_kernel(
        const float* __restrict__ h, float* __restrict__ of32, unsigned short* __restrict__ ob16,
        const float* __restrict__ colsum, const float* __restrict__ colsq,
        const float* __restrict__ gamma, const float* __restrict__ beta,
        float invN, int N) {
    int row = blockIdx.x * 4 + (threadIdx.x >> 6);
    int lane = threadIdx.x & 63;
    if (row >= N) return;
    int c0 = lane, c1 = lane + 64;
    float mu0 = colsum[c0] * invN;
    float var0 = colsq[c0] * invN - mu0 * mu0;
    float sc0 = gamma[c0] * rsqrtf(var0 + 1e-5f);
    float sh0 = beta[c0] - mu0 * sc0;
    float mu1 = colsum[c1] * invN;
    float var1 = colsq[c1] * invN - mu1 * mu1;
    float sc1 = gamma[c1] * rsqrtf(var1 + 1e-5f);
    float sh1 = beta[c1] - mu1 * sc1;
    size_t base = (size_t)row * DIM;
    float y0 = fmaxf(fmaf(h[base + c0], sc0, sh0), 0.f);
    float y1 = fmaxf(fmaf(h[base + c1], sc1, sh1), 0.f);
    float ss = y0 * y0 + y1 * y1;
    #pragma unroll
    for (int off = 32; off; off >>= 1) ss += __shfl_xor(ss, off);
    float inv = 1.0f / fmaxf(sqrtf(ss), 1e-12f);
    y0 *= inv; y1 *= inv;
    if (of32) { of32[base + c0] = y0; of32[base + c1] = y1; }
    if (ob16) { ob16[base + c0] = f2bf(y0); ob16[base + c1] = f2bf(y1); }
}

// ---------------------------------------------------------------- launch
extern "C" void kernel_launch(void* const* d_in, const int* in_sizes, int n_in,
                              void* d_out, int out_size, void* d_ws, size_t ws_size,
                              hipStream_t stream) {
    const float* x     = (const float*)d_in[0];
    const int*   ei    = (const int*)d_in[1];
    const float* pre_w = (const float*)d_in[2];
    const float* pre_g = (const float*)d_in[3];
    const float* pre_b = (const float*)d_in[4];
    const float* mp_wk = (const float*)d_in[5];
    const float* mp_wq = (const float*)d_in[6];
    const float* mp_wv = (const float*)d_in[7];
    const float* mp_ws = (const float*)d_in[8];
    const float* mp_g  = (const float*)d_in[9];
    const float* mp_b  = (const float*)d_in[10];
    const int N = in_sizes[0] / DIN;     // 50000
    const int E = in_sizes[1] / 2;       // 800000

    char* wsp = (char*)d_ws;
    size_t off = 0;
    auto alloc = [&](size_t bytes) {
        void* p = wsp + off;
        off = (off + bytes + 255) & ~(size_t)255;
        return p;
    };
    float*          hA   = (float*)alloc((size_t)N * DIM * 4);
    float*          hB   = (float*)alloc((size_t)N * DIM * 4);
    float*          Kb   = (float*)alloc((size_t)N * DIM * 4);
    unsigned int*   QVb  = (unsigned int*)alloc((size_t)N * 128 * 4);   // interleaved Q/V bf16 pairs
    unsigned short* hbf  = (unsigned short*)alloc((size_t)N * DIM * 2); // gemm input
    unsigned short* wt   = (unsigned short*)alloc((size_t)8 * DIM * DIM * 2);
    int*   counts = (int*)alloc((size_t)N * 4);
    int*   rp     = (int*)alloc((size_t)(N + 1) * 4);
    int*   cursor = (int*)alloc((size_t)N * 4);
    int*   bsums  = (int*)alloc(256);
    int*   boff   = (int*)alloc(256);
    int*   srcS   = (int*)alloc((size_t)E * 4);
    float* colsum = (float*)alloc(512);   // colsq contiguous right after
    float* colsq  = (float*)alloc(512);

    // --- CSR by dst (same edges both layers → build once per call)
    hipMemsetAsync(counts, 0, (size_t)N * 4, stream);
    hist_kernel<<<(E + 255) / 256, 256, 0, stream>>>(ei, counts, E);
    int G1 = (N + 1023) / 1024;
    scan1_kernel<<<G1, 1024, 0, stream>>>(counts, rp, bsums, N);
    scan2_kernel<<<1, 64, 0, stream>>>(bsums, boff, G1);
    scan3_kernel<<<G1, 1024, 0, stream>>>(counts, rp, cursor, boff, N, E);
    fill_kernel<<<(E + 255) / 256, 256, 0, stream>>>(ei, cursor, srcS, E);

    // --- weights -> bf16 transposed
    wconv_kernel<<<8, 128, 0, stream>>>(mp_wk, mp_wq, mp_wv, mp_ws, wt);

    // --- pre layer: Linear -> BN -> ReLU -> L2norm -> bf16
    pre_gemm_kernel<<<512, 128, 0, stream>>>(x, pre_w, hA, N);
    hipMemsetAsync(colsum, 0, 1024, stream);   // colsum + colsq
    colstats_kernel<<<512, 128, 0, stream>>>(hA, colsum, colsq, N);
    finalize_kernel<<<(N + 3) / 4, 256, 0, stream>>>(hA, nullptr, hbf,
                                                     colsum, colsq, pre_g, pre_b, 1.0f / N, N);

    // --- message-passing layers
    for (int l = 0; l < 2; ++l) {
        float* hout = (l == 0) ? hB : (float*)d_out;
        gemm_mfma_kernel<<<(N + GBM - 1) / GBM, 256, 0, stream>>>(
            hbf, wt + (size_t)l * 4 * DIM * DIM, Kb, QVb, hout, N);
        aggregate_kernel<<<N, 64, 0, stream>>>(Kb, QVb, rp, srcS, hout, N);
        hipMemsetAsync(colsum, 0, 1024, stream);
        colstats_kernel<<<512, 128, 0, stream>>>(hout, colsum, colsq, N);
        finalize_kernel<<<(N + 3) / 4, 256, 0, stream>>>(
            hout, (l == 1) ? hout : nullptr, (l == 0) ? hbf : nullptr,
            colsum, colsq, mp_g + l * DIM, mp_b + l * DIM, 1.0f / N, N);
    }
}

// Round 5
// 525.860 us; speedup vs baseline: 1.4850x; 1.0580x over previous
//
#include <hip/hip_runtime.h>
#include <math.h>

#define DIM 128
#define DIN 20

typedef __attribute__((ext_vector_type(8))) short bf16x8;
typedef __attribute__((ext_vector_type(4))) float f32x4;

__device__ __forceinline__ unsigned short f2bf(float x) {
    unsigned u = __float_as_uint(x);
    u = (u + 0x7FFF + ((u >> 16) & 1)) >> 16;   // RNE
    return (unsigned short)u;
}
__device__ __forceinline__ float sigf(float s) {
    return __builtin_amdgcn_rcpf(1.f + __expf(-s));
}
__device__ __forceinline__ float bflo(unsigned u) { return __uint_as_float(u << 16); }
__device__ __forceinline__ float bfhi(unsigned u) { return __uint_as_float(u & 0xffff0000u); }
__device__ __forceinline__ unsigned packbf(float a, float b) {
    return ((unsigned)f2bf(b) << 16) | f2bf(a);
}

// ---------------------------------------------------------------- CSR build
__global__ void hist_kernel(const int* __restrict__ ei, int* __restrict__ counts, int E) {
    int e = blockIdx.x * 256 + threadIdx.x;
    if (e < E) atomicAdd(&counts[ei[E + e]], 1);   // row 1 = dst
}

__global__ void scan1_kernel(const int* __restrict__ counts, int* __restrict__ incl,
                             int* __restrict__ blockSums, int N) {
    __shared__ int s[1024];
    int t = threadIdx.x;
    int i = blockIdx.x * 1024 + t;
    s[t] = (i < N) ? counts[i] : 0;
    __syncthreads();
    for (int off = 1; off < 1024; off <<= 1) {
        int x = (t >= off) ? s[t - off] : 0;
        __syncthreads();
        s[t] += x;
        __syncthreads();
    }
    if (i < N) incl[i] = s[t];
    if (t == 1023) blockSums[blockIdx.x] = s[1023];
}

__global__ void scan2_kernel(const int* __restrict__ blockSums, int* __restrict__ blockOff, int G) {
    int t = threadIdx.x;                 // 64 threads, G <= 64
    int v = (t < G) ? blockSums[t] : 0;
    int incl = v;
    #pragma unroll
    for (int off = 1; off < 64; off <<= 1) {
        int n = __shfl_up(incl, off);
        if (t >= off) incl += n;
    }
    if (t < G) blockOff[t] = incl - v;   // exclusive
}

__global__ void scan3_kernel(const int* __restrict__ counts, int* __restrict__ rp,
                             int* __restrict__ cursor, const int* __restrict__ blockOff,
                             int N, int E) {
    int i = blockIdx.x * 1024 + threadIdx.x;
    if (i < N) {
        int excl = rp[i] - counts[i] + blockOff[blockIdx.x];
        rp[i] = excl;
        cursor[i] = excl;
    }
    if (i == 0) rp[N] = E;
}

__global__ void fill_kernel(const int* __restrict__ ei, int* __restrict__ cursor,
                            int* __restrict__ srcS, int E) {
    int e = blockIdx.x * 256 + threadIdx.x;
    if (e >= E) return;
    int d = ei[E + e];
    int pos = atomicAdd(&cursor[d], 1);
    srcS[pos] = ei[e];                               // row 0 = src
}

// ---------------------------------------------------------------- weight convert: W[k][c] f32 -> Wt[c][k] bf16
__global__ __launch_bounds__(128) void wconv_kernel(const float* __restrict__ wk,
                                                    const float* __restrict__ wq,
                                                    const float* __restrict__ wv,
                                                    const float* __restrict__ ws,
                                                    unsigned short* __restrict__ wt) {
    int l = blockIdx.x >> 2, w = blockIdx.x & 3;
    const float* src = (w == 0 ? wk : w == 1 ? wq : w == 2 ? wv : ws) + (size_t)l * DIM * DIM;
    unsigned short* dst = wt + (size_t)blockIdx.x * DIM * DIM;
    int c = threadIdx.x;
    for (int k = 0; k < DIM; ++k) dst[c * DIM + k] = f2bf(src[k * DIM + c]);
}

// ---------------------------------------------------------------- pre GEMM + fused col stats
__global__ __launch_bounds__(128) void pre_gemm_kernel(const float* __restrict__ x,
                                                       const float* __restrict__ w,
                                                       float* __restrict__ h,
                                                       float* __restrict__ colsum,
                                                       float* __restrict__ colsq, int N) {
    __shared__ float ws_[DIN * DIM];
    __shared__ float xr[4][DIN];
    int tid = threadIdx.x;
    for (int i = tid; i < DIN * DIM; i += 128) ws_[i] = w[i];
    float s = 0.f, sq = 0.f;
    for (int r0 = blockIdx.x * 4; r0 < N; r0 += gridDim.x * 4) {
        __syncthreads();
        if (tid < 4 * DIN) {
            int rr = tid / DIN, kk = tid % DIN;
            if (r0 + rr < N) xr[rr][kk] = x[(size_t)(r0 + rr) * DIN + kk];
        }
        __syncthreads();
        #pragma unroll
        for (int rr = 0; rr < 4; ++rr) {
            int row = r0 + rr;
            if (row >= N) break;
            float acc = 0.f;
            #pragma unroll
            for (int k = 0; k < DIN; ++k) acc = fmaf(xr[rr][k], ws_[k * DIM + tid], acc);
            h[(size_t)row * DIM + tid] = acc;
            s += acc;
            sq = fmaf(acc, acc, sq);
        }
    }
    atomicAdd(&colsum[tid], s);
    atomicAdd(&colsq[tid], sq);
}

// ---------------------------------------------------------------- MFMA GEMM, swapped operands
// One block per 64-row tile; computes K,Q,V,S. K/S stored as packed bf16 pairs.
#define GBM 64
__global__ __launch_bounds__(256) void gemm_mfma_kernel(
        const unsigned short* __restrict__ A,    // [N][128] bf16
        const unsigned short* __restrict__ Wt,   // [4][128][128] bf16 (col-major k), this layer
        unsigned int* __restrict__ Kb,           // [N][64] bf16 pairs
        unsigned int* __restrict__ QV,           // [N][128] interleaved Q/V bf16 pairs
        unsigned int* __restrict__ Sb, int N) {  // [N][64] bf16 pairs
    __shared__ unsigned short Asw[GBM * DIM];    // 16 KB, swizzled
    int row0 = blockIdx.x * GBM;
    int tid = threadIdx.x;

    // stage A 64x128 bf16 in 16B granules: byte = r*256 + ((ch*16) ^ ((r&7)<<4))
    #pragma unroll
    for (int i = 0; i < 4; ++i) {
        int g = tid + i * 256;                   // 0..1023
        int r = g >> 4, ch = g & 15;
        int row = row0 + r;
        bf16x8 v = {0, 0, 0, 0, 0, 0, 0, 0};
        if (row < N) v = *(const bf16x8*)(A + (size_t)row * DIM + ch * 8);
        int dst = r * 256 + ((ch * 16) ^ ((r & 7) << 4));
        *(bf16x8*)((char*)Asw + dst) = v;
    }
    __syncthreads();

    int w = tid >> 6, l = tid & 63;
    int c0 = w * 32;
    int lj = l & 15, lg = l >> 4;

    // act frags (B operand): row = mf*16+lj, k = ks*32+lg*8 — reused for all 4 weights
    bf16x8 act[4][4];
    #pragma unroll
    for (int mf = 0; mf < 4; ++mf) {
        int r = mf * 16 + lj;
        #pragma unroll
        for (int ks = 0; ks < 4; ++ks) {
            int off = r * 256 + ((ks * 64 + lg * 16) ^ ((r & 7) << 4));
            act[mf][ks] = *(const bf16x8*)((char*)Asw + off);
        }
    }

    #pragma unroll
    for (int wgt = 0; wgt < 4; ++wgt) {          // 0:K 1:Q 2:V 3:S
        const unsigned short* W = Wt + (size_t)wgt * DIM * DIM;
        bf16x8 wf[2][4];                         // (A operand): col = c0+nf*16+lj, k = ks*32+lg*8
        #pragma unroll
        for (int nf = 0; nf < 2; ++nf)
            #pragma unroll
            for (int ks = 0; ks < 4; ++ks)
                wf[nf][ks] = *(const bf16x8*)(W + (size_t)(c0 + nf * 16 + lj) * DIM + ks * 32 + lg * 8);
        f32x4 acc[4][2] = {};
        #pragma unroll
        for (int mf = 0; mf < 4; ++mf)
            #pragma unroll
            for (int nf = 0; nf < 2; ++nf)
                #pragma unroll
                for (int ks = 0; ks < 4; ++ks)
                    acc[mf][nf] = __builtin_amdgcn_mfma_f32_16x16x32_bf16(
                        wf[nf][ks], act[mf][ks], acc[mf][nf], 0, 0, 0);
        // lane holds: row = row0 + mf*16 + lj ; cols = c0 + nf*16 + lg*4 + (0..3)
        #pragma unroll
        for (int mf = 0; mf < 4; ++mf) {
            int row = row0 + mf * 16 + lj;
            if (row < N) {
                #pragma unroll
                for (int nf = 0; nf < 2; ++nf) {
                    int col = c0 + nf * 16 + lg * 4;
                    f32x4 v = acc[mf][nf];
                    unsigned p0 = packbf(v[0], v[1]);
                    unsigned p1 = packbf(v[2], v[3]);
                    if (wgt == 0) {
                        *(uint2*)(Kb + (size_t)row * 64 + (col >> 1)) = make_uint2(p0, p1);
                    } else if (wgt == 3) {
                        *(uint2*)(Sb + (size_t)row * 64 + (col >> 1)) = make_uint2(p0, p1);
                    } else {
                        unsigned* U = QV + (size_t)row * 128;
                        // interleaved: U[2m]=Q pair m, U[2m+1]=V pair m
                        if (wgt == 1) { U[col]     = p0; U[col + 2] = p1; }
                        else          { U[col + 1] = p0; U[col + 3] = p1; }
                    }
                }
            }
        }
    }
}

// ---------------------------------------------------------------- pull aggregation (CSR by dst)
// 1 wave per dst. Lanes 0-31 = even edges, 32-63 = odd edges; lane covers cols 4*sub..4*sub+3
// via one uint4 (16B) per edge. Cross-half merge with shfl_xor(32).
__global__ __launch_bounds__(64) void aggregate_kernel(
        const unsigned int* __restrict__ Kb, const unsigned int* __restrict__ QV,
        const unsigned int* __restrict__ Sb,
        const int* __restrict__ rp, const int* __restrict__ srcS,
        float* __restrict__ out, int N) {
    int i = blockIdx.x;
    int l = threadIdx.x;
    int sub = l & 31;
    int half = l >> 5;
    uint2 kp = *(const uint2*)(Kb + (size_t)i * 64 + 2 * sub);
    float k0 = bflo(kp.x), k1 = bfhi(kp.x), k2 = bflo(kp.y), k3 = bfhi(kp.y);
    int beg = rp[i], end = rp[i + 1];
    int cnt = end - beg;
    int npairs = cnt >> 1;
    float a0 = 0, a1 = 0, a2 = 0, a3 = 0;
    int p = 0;
    for (; p + 2 <= npairs; p += 2) {            // 4 edges/iter (2 per half)
        int e = beg + 2 * p + half;
        int j0 = srcS[e];
        int j1 = srcS[e + 2];
        uint4 u0 = *(const uint4*)(QV + (size_t)j0 * 128 + 4 * sub);
        uint4 u1 = *(const uint4*)(QV + (size_t)j1 * 128 + 4 * sub);
        a0 = fmaf(sigf(k0 + bflo(u0.x)), bflo(u0.y), a0);
        a1 = fmaf(sigf(k1 + bfhi(u0.x)), bfhi(u0.y), a1);
        a2 = fmaf(sigf(k2 + bflo(u0.z)), bflo(u0.w), a2);
        a3 = fmaf(sigf(k3 + bfhi(u0.z)), bfhi(u0.w), a3);
        a0 = fmaf(sigf(k0 + bflo(u1.x)), bflo(u1.y), a0);
        a1 = fmaf(sigf(k1 + bfhi(u1.x)), bfhi(u1.y), a1);
        a2 = fmaf(sigf(k2 + bflo(u1.z)), bflo(u1.w), a2);
        a3 = fmaf(sigf(k3 + bfhi(u1.z)), bfhi(u1.w), a3);
    }
    for (; p < npairs; ++p) {
        int e = beg + 2 * p + half;
        int j = srcS[e];
        uint4 u = *(const uint4*)(QV + (size_t)j * 128 + 4 * sub);
        a0 = fmaf(sigf(k0 + bflo(u.x)), bflo(u.y), a0);
        a1 = fmaf(sigf(k1 + bfhi(u.x)), bfhi(u.y), a1);
        a2 = fmaf(sigf(k2 + bflo(u.z)), bflo(u.w), a2);
        a3 = fmaf(sigf(k3 + bfhi(u.z)), bfhi(u.w), a3);
    }
    if ((cnt & 1) && half == 0) {                // leftover edge -> half 0
        int j = srcS[beg + cnt - 1];
        uint4 u = *(const uint4*)(QV + (size_t)j * 128 + 4 * sub);
        a0 = fmaf(sigf(k0 + bflo(u.x)), bflo(u.y), a0);
        a1 = fmaf(sigf(k1 + bfhi(u.x)), bfhi(u.y), a1);
        a2 = fmaf(sigf(k2 + bflo(u.z)), bflo(u.w), a2);
        a3 = fmaf(sigf(k3 + bfhi(u.z)), bfhi(u.w), a3);
    }
    a0 += __shfl_xor(a0, 32);
    a1 += __shfl_xor(a1, 32);
    a2 += __shfl_xor(a2, 32);
    a3 += __shfl_xor(a3, 32);
    if (half == 0) {
        uint2 sp = *(const uint2*)(Sb + (size_t)i * 64 + 2 * sub);
        f32x4 o;
        o[0] = a0 + bflo(sp.x);
        o[1] = a1 + bfhi(sp.x);
        o[2] = a2 + bflo(sp.y);
        o[3] = a3 + bfhi(sp.y);
        *(f32x4*)(out + (size_t)i * DIM + 4 * sub) = o;
    }
}

// ---------------------------------------------------------------- BN column stats
__global__ __launch_bounds__(128) void colstats_kernel(const float* __restrict__ h,
                                                       float* __restrict__ colsum,
                                                       float* __restrict__ colsq, int N) {
    int c = threadIdx.x;
    float s = 0.f, sq = 0.f;
    for (int r = blockIdx.x; r < N; r += gridDim.x) {
        float v = h[(size_t)r * DIM + c];
        s += v;
        sq = fmaf(v, v, sq);
    }
    atomicAdd(&colsum[c], s);
    atomicAdd(&colsq[c], sq);
}

// ---------------------------------------------------------------- BN + ReLU + row L2 norm (+ optional bf16 out)
__global__ __launch_bounds__(256) void finalize_kernel(
        const float* __restrict__ h, float* __restrict__ of32, unsigned short* __restrict__ ob16,
        const float* __restrict__ colsum, const float* __restrict__ colsq,
        const float* __restrict__ gamma, const float* __restrict__ beta,
        float invN, int N) {
    int row = blockIdx.x * 4 + (threadIdx.x >> 6);
    int lane = threadIdx.x & 63;
    if (row >= N) return;
    int c0 = lane, c1 = lane + 64;
    float mu0 = colsum[c0] * invN;
    float var0 = colsq[c0] * invN - mu0 * mu0;
    float sc0 = gamma[c0] * rsqrtf(var0 + 1e-5f);
    float sh0 = beta[c0] - mu0 * sc0;
    float mu1 = colsum[c1] * invN;
    float var1 = colsq[c1] * invN - mu1 * mu1;
    float sc1 = gamma[c1] * rsqrtf(var1 + 1e-5f);
    float sh1 = beta[c1] - mu1 * sc1;
    size_t base = (size_t)row * DIM;
    float y0 = fmaxf(fmaf(h[base + c0], sc0, sh0), 0.f);
    float y1 = fmaxf(fmaf(h[base + c1], sc1, sh1), 0.f);
    float ss = y0 * y0 + y1 * y1;
    #pragma unroll
    for (int off = 32; off; off >>= 1) ss += __shfl_xor(ss, off);
    float inv = 1.0f / fmaxf(sqrtf(ss), 1e-12f);
    y0 *= inv; y1 *= inv;
    if (of32) { of32[base + c0] = y0; of32[base + c1] = y1; }
    if (ob16) { ob16[base + c0] = f2bf(y0); ob16[base + c1] = f2bf(y1); }
}

// ---------------------------------------------------------------- launch
extern "C" void kernel_launch(void* const* d_in, const int* in_sizes, int n_in,
                              void* d_out, int out_size, void* d_ws, size_t ws_size,
                              hipStream_t stream) {
    const float* x     = (const float*)d_in[0];
    const int*   ei    = (const int*)d_in[1];
    const float* pre_w = (const float*)d_in[2];
    const float* pre_g = (const float*)d_in[3];
    const float* pre_b = (const float*)d_in[4];
    const float* mp_wk = (const float*)d_in[5];
    const float* mp_wq = (const float*)d_in[6];
    const float* mp_wv = (const float*)d_in[7];
    const float* mp_ws = (const float*)d_in[8];
    const float* mp_g  = (const float*)d_in[9];
    const float* mp_b  = (const float*)d_in[10];
    const int N = in_sizes[0] / DIN;     // 50000
    const int E = in_sizes[1] / 2;       // 800000

    char* wsp = (char*)d_ws;
    size_t off = 0;
    auto alloc = [&](size_t bytes) {
        void* p = wsp + off;
        off = (off + bytes + 255) & ~(size_t)255;
        return p;
    };
    float*          hA   = (float*)alloc((size_t)N * DIM * 4);
    float*          hB   = (float*)alloc((size_t)N * DIM * 4);
    unsigned int*   Kb   = (unsigned int*)alloc((size_t)N * 64 * 4);    // bf16 pairs
    unsigned int*   QVb  = (unsigned int*)alloc((size_t)N * 128 * 4);   // interleaved Q/V bf16 pairs
    unsigned int*   Sb   = (unsigned int*)alloc((size_t)N * 64 * 4);    // bf16 pairs
    unsigned short* hbf  = (unsigned short*)alloc((size_t)N * DIM * 2); // gemm input
    unsigned short* wt   = (unsigned short*)alloc((size_t)8 * DIM * DIM * 2);
    int*   counts = (int*)alloc((size_t)N * 4);
    int*   rp     = (int*)alloc((size_t)(N + 1) * 4);
    int*   cursor = (int*)alloc((size_t)N * 4);
    int*   bsums  = (int*)alloc(256);
    int*   boff   = (int*)alloc(256);
    int*   srcS   = (int*)alloc((size_t)E * 4);
    float* colsum = (float*)alloc(512);   // colsq contiguous right after
    float* colsq  = (float*)alloc(512);

    // --- CSR by dst (same edges both layers → build once per call)
    hipMemsetAsync(counts, 0, (size_t)N * 4, stream);
    hist_kernel<<<(E + 255) / 256, 256, 0, stream>>>(ei, counts, E);
    int G1 = (N + 1023) / 1024;
    scan1_kernel<<<G1, 1024, 0, stream>>>(counts, rp, bsums, N);
    scan2_kernel<<<1, 64, 0, stream>>>(bsums, boff, G1);
    scan3_kernel<<<G1, 1024, 0, stream>>>(counts, rp, cursor, boff, N, E);
    fill_kernel<<<(E + 255) / 256, 256, 0, stream>>>(ei, cursor, srcS, E);

    // --- weights -> bf16 transposed
    wconv_kernel<<<8, 128, 0, stream>>>(mp_wk, mp_wq, mp_wv, mp_ws, wt);

    // --- pre layer: Linear(+stats) -> BN -> ReLU -> L2norm -> bf16
    hipMemsetAsync(colsum, 0, 1024, stream);   // colsum + colsq
    pre_gemm_kernel<<<512, 128, 0, stream>>>(x, pre_w, hA, colsum, colsq, N);
    finalize_kernel<<<(N + 3) / 4, 256, 0, stream>>>(hA, nullptr, hbf,
                                                     colsum, colsq, pre_g, pre_b, 1.0f / N, N);

    // --- message-passing layers
    for (int l = 0; l < 2; ++l) {
        float* hout = (l == 0) ? hB : (float*)d_out;
        gemm_mfma_kernel<<<(N + GBM - 1) / GBM, 256, 0, stream>>>(
            hbf, wt + (size_t)l * 4 * DIM * DIM, Kb, QVb, Sb, N);
        aggregate_kernel<<<N, 64, 0, stream>>>(Kb, QVb, Sb, rp, srcS, hout, N);
        hipMemsetAsync(colsum, 0, 1024, stream);
        colstats_kernel<<<512, 128, 0, stream>>>(hout, colsum, colsq, N);
        finalize_kernel<<<(N + 3) / 4, 256, 0, stream>>>(
            hout, (l == 1) ? hout : nullptr, (l == 0) ? hbf : nullptr,
            colsum, colsq, mp_g + l * DIM, mp_b + l * DIM, 1.0f / N, N);
    }
}

// Round 6
// 512.509 us; speedup vs baseline: 1.5236x; 1.0260x over previous
//
#include <hip/hip_runtime.h>
#include <math.h>

#define DIM 128
#define DIN 20

typedef __attribute__((ext_vector_type(8))) short bf16x8;
typedef __attribute__((ext_vector_type(4))) float f32x4;

__device__ __forceinline__ unsigned short f2bf(float x) {
    unsigned u = __float_as_uint(x);
    u = (u + 0x7FFF + ((u >> 16) & 1)) >> 16;   // RNE
    return (unsigned short)u;
}
__device__ __forceinline__ float sigf(float s) {
    return __builtin_amdgcn_rcpf(1.f + __expf(-s));
}
__device__ __forceinline__ float bflo(unsigned u) { return __uint_as_float(u << 16); }
__device__ __forceinline__ float bfhi(unsigned u) { return __uint_as_float(u & 0xffff0000u); }
__device__ __forceinline__ unsigned packbf(float a, float b) {
    return ((unsigned)f2bf(b) << 16) | f2bf(a);
}

// ---------------------------------------------------------------- CSR build
__global__ void hist_kernel(const int* __restrict__ ei, int* __restrict__ counts, int E) {
    int e = blockIdx.x * 256 + threadIdx.x;
    if (e < E) atomicAdd(&counts[ei[E + e]], 1);   // row 1 = dst
}

__global__ void scan1_kernel(const int* __restrict__ counts, int* __restrict__ incl,
                             int* __restrict__ blockSums, int N) {
    __shared__ int s[1024];
    int t = threadIdx.x;
    int i = blockIdx.x * 1024 + t;
    s[t] = (i < N) ? counts[i] : 0;
    __syncthreads();
    for (int off = 1; off < 1024; off <<= 1) {
        int x = (t >= off) ? s[t - off] : 0;
        __syncthreads();
        s[t] += x;
        __syncthreads();
    }
    if (i < N) incl[i] = s[t];
    if (t == 1023) blockSums[blockIdx.x] = s[1023];
}

// scan3 with scan2 folded in: each block recomputes its exclusive block offset
// from blockSums (G <= 64) with one wave.
__global__ void scan3_kernel(const int* __restrict__ counts, int* __restrict__ rp,
                             int* __restrict__ cursor, const int* __restrict__ blockSums,
                             int G, int N, int E) {
    __shared__ int boff_s;
    int t = threadIdx.x;
    if (t < 64) {
        int v = (t < G && t < blockIdx.x) ? blockSums[t] : 0;
        #pragma unroll
        for (int off = 32; off; off >>= 1) v += __shfl_xor(v, off);
        if (t == 0) boff_s = v;
    }
    __syncthreads();
    int i = blockIdx.x * 1024 + t;
    if (i < N) {
        int excl = rp[i] - counts[i] + boff_s;
        rp[i] = excl;
        cursor[i] = excl;
    }
    if (i == 0) rp[N] = E;
}

__global__ void fill_kernel(const int* __restrict__ ei, int* __restrict__ cursor,
                            int* __restrict__ srcS, int E) {
    int e = blockIdx.x * 256 + threadIdx.x;
    if (e >= E) return;
    int d = ei[E + e];
    int pos = atomicAdd(&cursor[d], 1);
    srcS[pos] = ei[e];                               // row 0 = src
}

// ---------------------------------------------------------------- weight convert: W[k][c] f32 -> Wt[c][k] bf16
__global__ __launch_bounds__(128) void wconv_kernel(const float* __restrict__ wk,
                                                    const float* __restrict__ wq,
                                                    const float* __restrict__ wv,
                                                    const float* __restrict__ ws,
                                                    unsigned short* __restrict__ wt) {
    int l = blockIdx.x >> 2, w = blockIdx.x & 3;
    const float* src = (w == 0 ? wk : w == 1 ? wq : w == 2 ? wv : ws) + (size_t)l * DIM * DIM;
    unsigned short* dst = wt + (size_t)blockIdx.x * DIM * DIM;
    int c = threadIdx.x;
    for (int k = 0; k < DIM; ++k) dst[c * DIM + k] = f2bf(src[k * DIM + c]);
}

// ---------------------------------------------------------------- pre GEMM + fused col stats
__global__ __launch_bounds__(128) void pre_gemm_kernel(const float* __restrict__ x,
                                                       const float* __restrict__ w,
                                                       float* __restrict__ h,
                                                       float* __restrict__ colsum,
                                                       float* __restrict__ colsq, int N) {
    __shared__ float ws_[DIN * DIM];
    __shared__ float xr[4][DIN];
    int tid = threadIdx.x;
    for (int i = tid; i < DIN * DIM; i += 128) ws_[i] = w[i];
    float s = 0.f, sq = 0.f;
    for (int r0 = blockIdx.x * 4; r0 < N; r0 += gridDim.x * 4) {
        __syncthreads();
        if (tid < 4 * DIN) {
            int rr = tid / DIN, kk = tid % DIN;
            if (r0 + rr < N) xr[rr][kk] = x[(size_t)(r0 + rr) * DIN + kk];
        }
        __syncthreads();
        #pragma unroll
        for (int rr = 0; rr < 4; ++rr) {
            int row = r0 + rr;
            if (row >= N) break;
            float acc = 0.f;
            #pragma unroll
            for (int k = 0; k < DIN; ++k) acc = fmaf(xr[rr][k], ws_[k * DIM + tid], acc);
            h[(size_t)row * DIM + tid] = acc;
            s += acc;
            sq = fmaf(acc, acc, sq);
        }
    }
    atomicAdd(&colsum[tid], s);
    atomicAdd(&colsq[tid], sq);
}

// ---------------------------------------------------------------- MFMA GEMM, swapped operands
// One block per 64-row tile, 512 threads = 8 waves; wave w covers 16 cols (c0 = w*16)
// for all 4 weights. K/S stored as packed bf16 pairs, Q/V interleaved pairs.
#define GBM 64
__global__ __launch_bounds__(512) void gemm_mfma_kernel(
        const unsigned short* __restrict__ A,    // [N][128] bf16
        const unsigned short* __restrict__ Wt,   // [4][128][128] bf16 (col-major k), this layer
        unsigned int* __restrict__ Kb,           // [N][64] bf16 pairs
        unsigned int* __restrict__ QV,           // [N][128] interleaved Q/V bf16 pairs
        unsigned int* __restrict__ Sb, int N) {  // [N][64] bf16 pairs
    __shared__ unsigned short Asw[GBM * DIM];    // 16 KB, swizzled
    int row0 = blockIdx.x * GBM;
    int tid = threadIdx.x;

    // stage A 64x128 bf16 in 16B granules: byte = r*256 + ((ch*16) ^ ((r&7)<<4))
    #pragma unroll
    for (int i = 0; i < 2; ++i) {
        int g = tid + i * 512;                   // 0..1023
        int r = g >> 4, ch = g & 15;
        int row = row0 + r;
        bf16x8 v = {0, 0, 0, 0, 0, 0, 0, 0};
        if (row < N) v = *(const bf16x8*)(A + (size_t)row * DIM + ch * 8);
        int dst = r * 256 + ((ch * 16) ^ ((r & 7) << 4));
        *(bf16x8*)((char*)Asw + dst) = v;
    }
    __syncthreads();

    int w = tid >> 6, l = tid & 63;
    int c0 = w * 16;
    int lj = l & 15, lg = l >> 4;

    // act frags (B operand): row = mf*16+lj, k = ks*32+lg*8 — reused for all 4 weights
    bf16x8 act[4][4];
    #pragma unroll
    for (int mf = 0; mf < 4; ++mf) {
        int r = mf * 16 + lj;
        #pragma unroll
        for (int ks = 0; ks < 4; ++ks) {
            int off = r * 256 + ((ks * 64 + lg * 16) ^ ((r & 7) << 4));
            act[mf][ks] = *(const bf16x8*)((char*)Asw + off);
        }
    }

    #pragma unroll
    for (int wgt = 0; wgt < 4; ++wgt) {          // 0:K 1:Q 2:V 3:S
        const unsigned short* W = Wt + (size_t)wgt * DIM * DIM;
        bf16x8 wf[4];                            // A operand: col = c0+lj, k = ks*32+lg*8
        #pragma unroll
        for (int ks = 0; ks < 4; ++ks)
            wf[ks] = *(const bf16x8*)(W + (size_t)(c0 + lj) * DIM + ks * 32 + lg * 8);
        f32x4 acc[4] = {};
        #pragma unroll
        for (int mf = 0; mf < 4; ++mf)
            #pragma unroll
            for (int ks = 0; ks < 4; ++ks)
                acc[mf] = __builtin_amdgcn_mfma_f32_16x16x32_bf16(
                    wf[ks], act[mf][ks], acc[mf], 0, 0, 0);
        // lane holds: row = row0 + mf*16 + lj ; cols = c0 + lg*4 + (0..3)
        #pragma unroll
        for (int mf = 0; mf < 4; ++mf) {
            int row = row0 + mf * 16 + lj;
            if (row < N) {
                int col = c0 + lg * 4;
                f32x4 v = acc[mf];
                unsigned p0 = packbf(v[0], v[1]);
                unsigned p1 = packbf(v[2], v[3]);
                if (wgt == 0) {
                    *(uint2*)(Kb + (size_t)row * 64 + (col >> 1)) = make_uint2(p0, p1);
                } else if (wgt == 3) {
                    *(uint2*)(Sb + (size_t)row * 64 + (col >> 1)) = make_uint2(p0, p1);
                } else {
                    unsigned* U = QV + (size_t)row * 128;
                    // interleaved: U[2m]=Q pair m, U[2m+1]=V pair m
                    if (wgt == 1) { U[col]     = p0; U[col + 2] = p1; }
                    else          { U[col + 1] = p0; U[col + 3] = p1; }
                }
            }
        }
    }
}

// ---------------------------------------------------------------- pull aggregation (CSR by dst)
// 256 threads = 4 nodes/block, 1 wave per node. Lanes 0-31 = even edges, 32-63 = odd;
// lane covers cols 4*sub..4*sub+3 via one uint4 per edge. 8 edges in flight per wave.
__global__ __launch_bounds__(256) void aggregate_kernel(
        const unsigned int* __restrict__ Kb, const unsigned int* __restrict__ QV,
        const unsigned int* __restrict__ Sb,
        const int* __restrict__ rp, const int* __restrict__ srcS,
        float* __restrict__ out, int N) {
    int node = blockIdx.x * 4 + (threadIdx.x >> 6);
    if (node >= N) return;
    int l = threadIdx.x & 63;
    int sub = l & 31;
    int half = l >> 5;
    uint2 kp = *(const uint2*)(Kb + (size_t)node * 64 + 2 * sub);
    float k0 = bflo(kp.x), k1 = bfhi(kp.x), k2 = bflo(kp.y), k3 = bfhi(kp.y);
    int beg = rp[node], end = rp[node + 1];
    int cnt = end - beg;
    int npairs = cnt >> 1;
    float a0 = 0, a1 = 0, a2 = 0, a3 = 0;
    int p = 0;
    for (; p + 4 <= npairs; p += 4) {            // 8 edges/iter (4 per half)
        int e = beg + 2 * p + half;
        int j0 = srcS[e];
        int j1 = srcS[e + 2];
        int j2 = srcS[e + 4];
        int j3 = srcS[e + 6];
        uint4 u0 = *(const uint4*)(QV + (size_t)j0 * 128 + 4 * sub);
        uint4 u1 = *(const uint4*)(QV + (size_t)j1 * 128 + 4 * sub);
        uint4 u2 = *(const uint4*)(QV + (size_t)j2 * 128 + 4 * sub);
        uint4 u3 = *(const uint4*)(QV + (size_t)j3 * 128 + 4 * sub);
        a0 = fmaf(sigf(k0 + bflo(u0.x)), bflo(u0.y), a0);
        a1 = fmaf(sigf(k1 + bfhi(u0.x)), bfhi(u0.y), a1);
        a2 = fmaf(sigf(k2 + bflo(u0.z)), bflo(u0.w), a2);
        a3 = fmaf(sigf(k3 + bfhi(u0.z)), bfhi(u0.w), a3);
        a0 = fmaf(sigf(k0 + bflo(u1.x)), bflo(u1.y), a0);
        a1 = fmaf(sigf(k1 + bfhi(u1.x)), bfhi(u1.y), a1);
        a2 = fmaf(sigf(k2 + bflo(u1.z)), bflo(u1.w), a2);
        a3 = fmaf(sigf(k3 + bfhi(u1.z)), bfhi(u1.w), a3);
        a0 = fmaf(sigf(k0 + bflo(u2.x)), bflo(u2.y), a0);
        a1 = fmaf(sigf(k1 + bfhi(u2.x)), bfhi(u2.y), a1);
        a2 = fmaf(sigf(k2 + bflo(u2.z)), bflo(u2.w), a2);
        a3 = fmaf(sigf(k3 + bfhi(u2.z)), bfhi(u2.w), a3);
        a0 = fmaf(sigf(k0 + bflo(u3.x)), bflo(u3.y), a0);
        a1 = fmaf(sigf(k1 + bfhi(u3.x)), bfhi(u3.y), a1);
        a2 = fmaf(sigf(k2 + bflo(u3.z)), bflo(u3.w), a2);
        a3 = fmaf(sigf(k3 + bfhi(u3.z)), bfhi(u3.w), a3);
    }
    for (; p < npairs; ++p) {
        int e = beg + 2 * p + half;
        int j = srcS[e];
        uint4 u = *(const uint4*)(QV + (size_t)j * 128 + 4 * sub);
        a0 = fmaf(sigf(k0 + bflo(u.x)), bflo(u.y), a0);
        a1 = fmaf(sigf(k1 + bfhi(u.x)), bfhi(u.y), a1);
        a2 = fmaf(sigf(k2 + bflo(u.z)), bflo(u.w), a2);
        a3 = fmaf(sigf(k3 + bfhi(u.z)), bfhi(u.w), a3);
    }
    if ((cnt & 1) && half == 0) {                // leftover edge -> half 0
        int j = srcS[beg + cnt - 1];
        uint4 u = *(const uint4*)(QV + (size_t)j * 128 + 4 * sub);
        a0 = fmaf(sigf(k0 + bflo(u.x)), bflo(u.y), a0);
        a1 = fmaf(sigf(k1 + bfhi(u.x)), bfhi(u.y), a1);
        a2 = fmaf(sigf(k2 + bflo(u.z)), bflo(u.w), a2);
        a3 = fmaf(sigf(k3 + bfhi(u.z)), bfhi(u.w), a3);
    }
    a0 += __shfl_xor(a0, 32);
    a1 += __shfl_xor(a1, 32);
    a2 += __shfl_xor(a2, 32);
    a3 += __shfl_xor(a3, 32);
    if (half == 0) {
        uint2 sp = *(const uint2*)(Sb + (size_t)node * 64 + 2 * sub);
        f32x4 o;
        o[0] = a0 + bflo(sp.x);
        o[1] = a1 + bfhi(sp.x);
        o[2] = a2 + bflo(sp.y);
        o[3] = a3 + bfhi(sp.y);
        *(f32x4*)(out + (size_t)node * DIM + 4 * sub) = o;
    }
}

// ---------------------------------------------------------------- BN column stats
__global__ __launch_bounds__(128) void colstats_kernel(const float* __restrict__ h,
                                                       float* __restrict__ colsum,
                                                       float* __restrict__ colsq, int N) {
    int c = threadIdx.x;
    float s = 0.f, sq = 0.f;
    for (int r = blockIdx.x; r < N; r += gridDim.x) {
        float v = h[(size_t)r * DIM + c];
        s += v;
        sq = fmaf(v, v, sq);
    }
    atomicAdd(&colsum[c], s);
    atomicAdd(&colsq[c], sq);
}

// ---------------------------------------------------------------- BN + ReLU + row L2 norm (+ optional bf16 out)
__global__ __launch_bounds__(256) void finalize_kernel(
        const float* __restrict__ h, float* __restrict__ of32, unsigned short* __restrict__ ob16,
        const float* __restrict__ colsum, const float* __restrict__ colsq,
        const float* __restrict__ gamma, const float* __restrict__ beta,
        float invN, int N) {
    int row = blockIdx.x * 4 + (threadIdx.x >> 6);
    int lane = threadIdx.x & 63;
    if (row >= N) return;
    int c0 = lane, c1 = lane + 64;
    float mu0 = colsum[c0] * invN;
    float var0 = colsq[c0] * invN - mu0 * mu0;
    float sc0 = gamma[c0] * rsqrtf(var0 + 1e-5f);
    float sh0 = beta[c0] - mu0 * sc0;
    float mu1 = colsum[c1] * invN;
    float var1 = colsq[c1] * invN - mu1 * mu1;
    float sc1 = gamma[c1] * rsqrtf(var1 + 1e-5f);
    float sh1 = beta[c1] - mu1 * sc1;
    size_t base = (size_t)row * DIM;
    float y0 = fmaxf(fmaf(h[base + c0], sc0, sh0), 0.f);
    float y1 = fmaxf(fmaf(h[base + c1], sc1, sh1), 0.f);
    float ss = y0 * y0 + y1 * y1;
    #pragma unroll
    for (int off = 32; off; off >>= 1) ss += __shfl_xor(ss, off);
    float inv = 1.0f / fmaxf(sqrtf(ss), 1e-12f);
    y0 *= inv; y1 *= inv;
    if (of32) { of32[base + c0] = y0; of32[base + c1] = y1; }
    if (ob16) { ob16[base + c0] = f2bf(y0); ob16[base + c1] = f2bf(y1); }
}

// ---------------------------------------------------------------- launch
extern "C" void kernel_launch(void* const* d_in, const int* in_sizes, int n_in,
                              void* d_out, int out_size, void* d_ws, size_t ws_size,
                              hipStream_t stream) {
    const float* x     = (const float*)d_in[0];
    const int*   ei    = (const int*)d_in[1];
    const float* pre_w = (const float*)d_in[2];
    const float* pre_g = (const float*)d_in[3];
    const float* pre_b = (const float*)d_in[4];
    const float* mp_wk = (const float*)d_in[5];
    const float* mp_wq = (const float*)d_in[6];
    const float* mp_wv = (const float*)d_in[7];
    const float* mp_ws = (const float*)d_in[8];
    const float* mp_g  = (const float*)d_in[9];
    const float* mp_b  = (const float*)d_in[10];
    const int N = in_sizes[0] / DIN;     // 50000
    const int E = in_sizes[1] / 2;       // 800000

    char* wsp = (char*)d_ws;
    size_t off = 0;
    auto alloc = [&](size_t bytes) {
        void* p = wsp + off;
        off = (off + bytes + 255) & ~(size_t)255;
        return p;
    };
    float*          hA   = (float*)alloc((size_t)N * DIM * 4);
    float*          hB   = (float*)alloc((size_t)N * DIM * 4);
    unsigned int*   Kb   = (unsigned int*)alloc((size_t)N * 64 * 4);    // bf16 pairs
    unsigned int*   QVb  = (unsigned int*)alloc((size_t)N * 128 * 4);   // interleaved Q/V bf16 pairs
    unsigned int*   Sb   = (unsigned int*)alloc((size_t)N * 64 * 4);    // bf16 pairs
    unsigned short* hbf  = (unsigned short*)alloc((size_t)N * DIM * 2); // gemm input
    unsigned short* wt   = (unsigned short*)alloc((size_t)8 * DIM * DIM * 2);
    // zero-region: counts + 3x colsum + 3x colsq (contiguous, one memset)
    int*   counts = (int*)alloc((size_t)N * 4);
    float* colsum = (float*)alloc(3 * 128 * 4);
    float* colsq  = (float*)alloc(3 * 128 * 4);
    size_t zero_bytes = (size_t)((char*)colsq + 3 * 128 * 4 - (char*)counts);
    int*   rp     = (int*)alloc((size_t)(N + 1) * 4);
    int*   cursor = (int*)alloc((size_t)N * 4);
    int*   bsums  = (int*)alloc(256);
    int*   srcS   = (int*)alloc((size_t)E * 4);

    hipMemsetAsync(counts, 0, zero_bytes, stream);

    // --- CSR by dst (same edges both layers → build once per call)
    hist_kernel<<<(E + 255) / 256, 256, 0, stream>>>(ei, counts, E);
    int G1 = (N + 1023) / 1024;
    scan1_kernel<<<G1, 1024, 0, stream>>>(counts, rp, bsums, N);
    scan3_kernel<<<G1, 1024, 0, stream>>>(counts, rp, cursor, bsums, G1, N, E);
    fill_kernel<<<(E + 255) / 256, 256, 0, stream>>>(ei, cursor, srcS, E);

    // --- weights -> bf16 transposed
    wconv_kernel<<<8, 128, 0, stream>>>(mp_wk, mp_wq, mp_wv, mp_ws, wt);

    // --- pre layer: Linear(+stats) -> BN -> ReLU -> L2norm -> bf16
    pre_gemm_kernel<<<512, 128, 0, stream>>>(x, pre_w, hA, colsum, colsq, N);
    finalize_kernel<<<(N + 3) / 4, 256, 0, stream>>>(hA, nullptr, hbf,
                                                     colsum, colsq, pre_g, pre_b, 1.0f / N, N);

    // --- message-passing layers
    for (int l = 0; l < 2; ++l) {
        float* hout = (l == 0) ? hB : (float*)d_out;
        float* cs = colsum + (l + 1) * 128;
        float* cq = colsq + (l + 1) * 128;
        gemm_mfma_kernel<<<(N + GBM - 1) / GBM, 512, 0, stream>>>(
            hbf, wt + (size_t)l * 4 * DIM * DIM, Kb, QVb, Sb, N);
        aggregate_kernel<<<(N + 3) / 4, 256, 0, stream>>>(Kb, QVb, Sb, rp, srcS, hout, N);
        colstats_kernel<<<512, 128, 0, stream>>>(hout, cs, cq, N);
        finalize_kernel<<<(N + 3) / 4, 256, 0, stream>>>(
            hout, (l == 1) ? hout : nullptr, (l == 0) ? hbf : nullptr,
            cs, cq, mp_g + l * DIM, mp_b + l * DIM, 1.0f / N, N);
    }
}